// Round 9
// baseline (432.021 us; speedup 1.0000x reference)
//
#include <hip/hip_runtime.h>
#include <math.h>

#define NTN 32768
#define BB 16
#define NN 2048
#define IN_CH 128
#define HC 256
#define EREAL 524288
#define ETOT (EREAL + NTN)
#define FC0 1024
#define FC1 512
#define OMIC 128
#define OUTD 2
#define CAP 96

#define PREP_BLKS (NTN / 4)
#define DEG_BLKS (EREAL / 256)
#define CASTW_BLKS ((HC * IN_CH + HC * HC) / 256)

typedef __attribute__((ext_vector_type(8))) short bf16x8;
typedef __attribute__((ext_vector_type(4))) float f32x4;

static __device__ __forceinline__ float wave_sum(float v) {
    for (int o = 32; o; o >>= 1) v += __shfl_xor(v, o);
    return v;
}
static __device__ __forceinline__ unsigned short f2bf(float f) {
    unsigned u = __float_as_uint(f);
    unsigned r = (u + 0x7fff + ((u >> 16) & 1)) >> 16;
    return (unsigned short)r;
}
static __device__ __forceinline__ void fma8(uint4 v, float e, float* acc) {
    acc[0] += __uint_as_float(v.x << 16) * e;
    acc[1] += __uint_as_float(v.x & 0xffff0000u) * e;
    acc[2] += __uint_as_float(v.y << 16) * e;
    acc[3] += __uint_as_float(v.y & 0xffff0000u) * e;
    acc[4] += __uint_as_float(v.z << 16) * e;
    acc[5] += __uint_as_float(v.z & 0xffff0000u) * e;
    acc[6] += __uint_as_float(v.w << 16) * e;
    acc[7] += __uint_as_float(v.w & 0xffff0000u) * e;
}

// ---- fused: x->bf16 + mean | deg count + edge slot | weight transpose-casts ----
__global__ __launch_bounds__(256) void k_pre(
    const float* __restrict__ x, unsigned short* __restrict__ xb, float* __restrict__ xmean,
    const int* __restrict__ ei, int* __restrict__ deg, int* __restrict__ epos,
    const float* __restrict__ w1, const float* __restrict__ w2,
    unsigned short* __restrict__ w1t, unsigned short* __restrict__ w2t) {
    int b = blockIdx.x, t = threadIdx.x;
    if (b < PREP_BLKS) {
        int wave = t >> 6, lane = t & 63;
        int n = b * 4 + wave;
        float2 v = *(const float2*)(x + (size_t)n * IN_CH + lane * 2);
        ushort2 o;
        o.x = f2bf(v.x); o.y = f2bf(v.y);
        *(ushort2*)(xb + (size_t)n * IN_CH + lane * 2) = o;
        float s = wave_sum(v.x + v.y);
        if (lane == 0) xmean[n] = s * (1.0f / 128.0f);
    } else if (b < PREP_BLKS + DEG_BLKS) {
        int e = (b - PREP_BLKS) * 256 + t;
        int d = ei[EREAL + e];
        epos[e] = atomicAdd(&deg[d], 1);
    } else {
        int idx = (b - PREP_BLKS - DEG_BLKS) * 256 + t;
        if (idx < HC * IN_CH) {
            int n = idx / IN_CH, k = idx % IN_CH;
            w1t[idx] = f2bf(w1[(size_t)k * HC + n]);
        } else {
            int j = idx - HC * IN_CH;
            int n = j / HC, k = j % HC;
            w2t[j] = f2bf(w2[(size_t)k * HC + n]);
        }
    }
}

// ---- scan degrees -> rowptr; write self-loop at slot 0 of each segment ----
__global__ __launch_bounds__(1024) void k_scan(const int* __restrict__ deg, int* __restrict__ rowptr,
                                               int* __restrict__ csr) {
    __shared__ int sd[1024];
    int t = threadIdx.x;
    int base = t * 32;
    int loc[32];
    int s = 0;
#pragma unroll
    for (int j = 0; j < 32; j++) { int d = deg[base + j] + 1; loc[j] = d; s += d; }
    sd[t] = s; __syncthreads();
    for (int o = 1; o < 1024; o <<= 1) {
        int v = (t >= o) ? sd[t - o] : 0;
        __syncthreads();
        sd[t] += v;
        __syncthreads();
    }
    int run = sd[t] - s;  // exclusive prefix
#pragma unroll
    for (int j = 0; j < 32; j++) {
        rowptr[base + j] = run;
        csr[run] = base + j;   // self-loop at slot 0
        run += loc[j];
    }
    if (t == 1023) rowptr[NTN] = run;
}

// ---- atomic-free CSR fill using precomputed slots ----
__global__ void k_fill(const int* __restrict__ ei, const int* __restrict__ epos,
                       const int* __restrict__ rowptr, int* __restrict__ csr) {
    int e = blockIdx.x * 256 + threadIdx.x;
    if (e >= EREAL) return;
    int s = ei[e], d = ei[EREAL + e];
    csr[rowptr[d] + 1 + epos[e]] = s;
}

// ---- bf16 MFMA GEMM: C[M,256] = A[M,K] @ Bt[256,K]^T, fused att head-dots ----
__global__ __launch_bounds__(256) void k_gemm_mfma(
    const unsigned short* __restrict__ A, const unsigned short* __restrict__ Bt, int K,
    const float* __restrict__ attS, const float* __restrict__ attD,
    unsigned short* __restrict__ Cout, float* __restrict__ aS, float* __restrict__ aD) {
    __shared__ unsigned short As[128][72];
    __shared__ unsigned short Bs[64][72];
    const int t = threadIdx.x;
    const int lane = t & 63, wave = t >> 6;
    const int quad = lane >> 4, l16 = lane & 15;
    const int bx = blockIdx.x, by = blockIdx.y;
    const int arow = t >> 1, acol = (t & 1) * 32;
    const int brow = t >> 2, bcol = (t & 3) * 16;
    const unsigned short* Ag = A + (size_t)(by * 128 + arow) * K + acol;
    const unsigned short* Bg = Bt + (size_t)(bx * 64 + brow) * K + bcol;
    f32x4 acc[2][4] = {};
    for (int k0 = 0; k0 < K; k0 += 64) {
        uint4 a0 = *(const uint4*)(Ag + k0);
        uint4 a1 = *(const uint4*)(Ag + k0 + 8);
        uint4 a2 = *(const uint4*)(Ag + k0 + 16);
        uint4 a3 = *(const uint4*)(Ag + k0 + 24);
        uint4 b0 = *(const uint4*)(Bg + k0);
        uint4 b1 = *(const uint4*)(Bg + k0 + 8);
        __syncthreads();
        *(uint4*)&As[arow][acol +  0] = a0;
        *(uint4*)&As[arow][acol +  8] = a1;
        *(uint4*)&As[arow][acol + 16] = a2;
        *(uint4*)&As[arow][acol + 24] = a3;
        *(uint4*)&Bs[brow][bcol +  0] = b0;
        *(uint4*)&Bs[brow][bcol +  8] = b1;
        __syncthreads();
#pragma unroll
        for (int kc = 0; kc < 64; kc += 32) {
            bf16x8 af[2], bfr[4];
#pragma unroll
            for (int mt = 0; mt < 2; mt++)
                af[mt] = *(const bf16x8*)&As[wave * 32 + mt * 16 + l16][kc + quad * 8];
#pragma unroll
            for (int nt = 0; nt < 4; nt++)
                bfr[nt] = *(const bf16x8*)&Bs[nt * 16 + l16][kc + quad * 8];
#pragma unroll
            for (int mt = 0; mt < 2; mt++)
#pragma unroll
                for (int nt = 0; nt < 4; nt++)
                    acc[mt][nt] = __builtin_amdgcn_mfma_f32_16x16x32_bf16(af[mt], bfr[nt], acc[mt][nt], 0, 0, 0);
        }
    }
    float as_l[4], ad_l[4];
#pragma unroll
    for (int nt = 0; nt < 4; nt++) {
        int gcol = bx * 64 + nt * 16 + l16;
        as_l[nt] = attS[gcol];
        ad_l[nt] = attD[gcol];
    }
#pragma unroll
    for (int mt = 0; mt < 2; mt++) {
#pragma unroll
        for (int reg = 0; reg < 4; reg++) {
            int grow = by * 128 + wave * 32 + mt * 16 + quad * 4 + reg;
            float ps = 0.f, pd = 0.f;
#pragma unroll
            for (int nt = 0; nt < 4; nt++) {
                float v = acc[mt][nt][reg];
                Cout[(size_t)grow * HC + bx * 64 + nt * 16 + l16] = f2bf(v);
                ps += v * as_l[nt];
                pd += v * ad_l[nt];
            }
            for (int o = 8; o; o >>= 1) { ps += __shfl_xor(ps, o); pd += __shfl_xor(pd, o); }
            if (l16 == 0) { aS[grow * 4 + bx] = ps; aD[grow * 4 + bx] = pd; }
        }
    }
}

// ---- attention aggregate: 2 nodes/block, 2 waves/node; half-wave pairing, unroll-8 ----
__global__ __launch_bounds__(256) void k_agg(
    const unsigned short* __restrict__ xw, const float* __restrict__ aS, const float* __restrict__ aD,
    const int* __restrict__ rowptr, const int* __restrict__ csr,
    const float* __restrict__ bias, const float* __restrict__ poolw, const float* __restrict__ poolb,
    unsigned short* __restrict__ hout, float* __restrict__ xpre) {
    __shared__ float ea_s[2][CAP][4];
    __shared__ float part[2][2][256];
    __shared__ float lpart[2][2][4];
    int t = threadIdx.x;
    int wave = t >> 6, lane = t & 63;
    int nd = wave >> 1, half = wave & 1;
    int n = blockIdx.x * 2 + nd;
    int beg = rowptr[n], end = rowptr[n + 1];
    int deg = end - beg;
    int mid = beg + ((deg + 1) >> 1);
    int wbeg = half ? mid : beg;
    int wend = half ? end : mid;
    float4 ad4 = *(const float4*)(aD + n * 4);
    float l0 = 0.f, l1 = 0.f, l2 = 0.f, l3 = 0.f;
    for (int i = wbeg + lane; i < wend; i += 64) {
        int s = csr[i];
        float4 as4 = *(const float4*)(aS + s * 4);
        float a0 = as4.x + ad4.x; a0 = a0 > 0.f ? a0 : 0.2f * a0; float e0 = __expf(a0);
        float a1 = as4.y + ad4.y; a1 = a1 > 0.f ? a1 : 0.2f * a1; float e1 = __expf(a1);
        float a2 = as4.z + ad4.z; a2 = a2 > 0.f ? a2 : 0.2f * a2; float e2 = __expf(a2);
        float a3 = as4.w + ad4.w; a3 = a3 > 0.f ? a3 : 0.2f * a3; float e3 = __expf(a3);
        l0 += e0; l1 += e1; l2 += e2; l3 += e3;
        int j = i - beg;
        if (j < CAP) {
            float4 e4; e4.x = e0; e4.y = e1; e4.z = e2; e4.w = e3;
            *(float4*)&ea_s[nd][j][0] = e4;
        }
    }
    l0 = wave_sum(l0); l1 = wave_sum(l1); l2 = wave_sum(l2); l3 = wave_sum(l3);
    if (lane == 0) {
        lpart[nd][half][0] = l0; lpart[nd][half][1] = l1;
        lpart[nd][half][2] = l2; lpart[nd][half][3] = l3;
    }
    __syncthreads();
    int l31 = lane & 31, hi = lane >> 5;
    int head = l31 >> 3;
    float ilh = 1.0f / (lpart[nd][0][head] + lpart[nd][1][head] + 1e-16f);
    float adh = head == 0 ? ad4.x : head == 1 ? ad4.y : head == 2 ? ad4.z : ad4.w;
    float accA[8] = {}, accB[8] = {};
    const unsigned short* xwc = xw + l31 * 8;
    if (deg <= CAP) {
        int i = wbeg;
        // unroll-8: 4 edges per half-wave iteration, 4 gathers in flight
        for (; i + 8 <= wend; i += 8) {
            int s0 = csr[i + hi];
            int s1 = csr[i + 2 + hi];
            int s2 = csr[i + 4 + hi];
            int s3 = csr[i + 6 + hi];
            float e0 = ea_s[nd][i + hi - beg][head];
            float e1 = ea_s[nd][i + 2 + hi - beg][head];
            float e2 = ea_s[nd][i + 4 + hi - beg][head];
            float e3 = ea_s[nd][i + 6 + hi - beg][head];
            uint4 v0 = *(const uint4*)(xwc + (size_t)s0 * HC);
            uint4 v1 = *(const uint4*)(xwc + (size_t)s1 * HC);
            uint4 v2 = *(const uint4*)(xwc + (size_t)s2 * HC);
            uint4 v3 = *(const uint4*)(xwc + (size_t)s3 * HC);
            fma8(v0, e0, accA);
            fma8(v1, e1, accB);
            fma8(v2, e2, accA);
            fma8(v3, e3, accB);
        }
        for (; i < wend; i += 2) {
            int idx = i + hi;
            bool ok = idx < wend;
            int sA = csr[ok ? idx : wbeg];
            float eA = ok ? ea_s[nd][idx - beg][head] : 0.f;
            uint4 vA = *(const uint4*)(xwc + (size_t)sA * HC);
            fma8(vA, eA, accA);
        }
    } else {
        for (int i = wbeg; i < wend; i += 2) {
            int idx = i + hi;
            bool ok = idx < wend;
            int sA = csr[ok ? idx : wbeg];
            float a = aS[sA * 4 + head] + adh;
            a = a > 0.f ? a : 0.2f * a;
            float eA = ok ? __expf(a) : 0.f;
            uint4 vA = *(const uint4*)(xwc + (size_t)sA * HC);
            fma8(vA, eA, accA);
        }
    }
    float r8[8];
#pragma unroll
    for (int j = 0; j < 8; j++) {
        float v = accA[j] + accB[j];
        v += __shfl_xor(v, 32);
        r8[j] = v;
    }
    if (hi == 0) {
        float4 q0; q0.x = r8[0]; q0.y = r8[1]; q0.z = r8[2]; q0.w = r8[3];
        float4 q1; q1.x = r8[4]; q1.y = r8[5]; q1.z = r8[6]; q1.w = r8[7];
        *(float4*)&part[nd][half][l31 * 8] = q0;
        *(float4*)&part[nd][half][l31 * 8 + 4] = q1;
    }
    __syncthreads();
    if (half == 0 && hi == 0) {
        float4 p00 = *(const float4*)&part[nd][0][l31 * 8];
        float4 p01 = *(const float4*)&part[nd][0][l31 * 8 + 4];
        float4 p10 = *(const float4*)&part[nd][1][l31 * 8];
        float4 p11 = *(const float4*)&part[nd][1][l31 * 8 + 4];
        float4 b0 = *(const float4*)(bias + l31 * 8);
        float4 b1 = *(const float4*)(bias + l31 * 8 + 4);
        float r[8];
        r[0] = (p00.x + p10.x) * ilh + b0.x;
        r[1] = (p00.y + p10.y) * ilh + b0.y;
        r[2] = (p00.z + p10.z) * ilh + b0.z;
        r[3] = (p00.w + p10.w) * ilh + b0.w;
        r[4] = (p01.x + p11.x) * ilh + b1.x;
        r[5] = (p01.y + p11.y) * ilh + b1.y;
        r[6] = (p01.z + p11.z) * ilh + b1.z;
        r[7] = (p01.w + p11.w) * ilh + b1.w;
#pragma unroll
        for (int j = 0; j < 8; j++) r[j] = r[j] > 0.f ? r[j] : expm1f(r[j]);
        if (hout) {
            uint4 o;
            o.x = (unsigned)f2bf(r[0]) | ((unsigned)f2bf(r[1]) << 16);
            o.y = (unsigned)f2bf(r[2]) | ((unsigned)f2bf(r[3]) << 16);
            o.z = (unsigned)f2bf(r[4]) | ((unsigned)f2bf(r[5]) << 16);
            o.w = (unsigned)f2bf(r[6]) | ((unsigned)f2bf(r[7]) << 16);
            *(uint4*)(hout + (size_t)n * HC + l31 * 8) = o;
        }
        float4 w0 = *(const float4*)(poolw + l31 * 8);
        float4 w1v = *(const float4*)(poolw + l31 * 8 + 4);
        float p = r[0] * w0.x + r[1] * w0.y + r[2] * w0.z + r[3] * w0.w +
                  r[4] * w1v.x + r[5] * w1v.y + r[6] * w1v.z + r[7] * w1v.w;
        for (int o = 16; o; o >>= 1) p += __shfl_xor(p, o);
        if (l31 == 0) xpre[n] = p + poolb[0];
    }
}

// ---- LayerNorm x3: blocks 0-15 xmean->col0, 16-31 x1pre->col1, 32-47 x2pre->col2 ----
__global__ __launch_bounds__(256) void k_ln3(const float* __restrict__ xmean, const float* __restrict__ x1pre,
                                             const float* __restrict__ x2pre, const float* __restrict__ lw,
                                             const float* __restrict__ lb, float* __restrict__ feat) {
    __shared__ float r0[256], r1[256];
    int b = blockIdx.x, t = threadIdx.x;
    int row = b & 15, seg = b >> 4;
    const float* src = (seg == 0 ? xmean : seg == 1 ? x1pre : x2pre) + (size_t)row * NN;
    float* dst = feat + (size_t)row * (3 * NN) + seg * NN;
    float v[8];
    float s = 0.f, s2 = 0.f;
#pragma unroll
    for (int j = 0; j < 8; j++) {
        float x = src[t + j * 256];
        v[j] = x; s += x; s2 += x * x;
    }
    r0[t] = s; r1[t] = s2; __syncthreads();
    for (int o = 128; o; o >>= 1) {
        if (t < o) { r0[t] += r0[t + o]; r1[t] += r1[t + o]; }
        __syncthreads();
    }
    float mu = r0[0] * (1.0f / NN);
    float var = r1[0] * (1.0f / NN) - mu * mu;
    float rs = rsqrtf(var + 1e-5f);
#pragma unroll
    for (int j = 0; j < 8; j++) {
        int idx = t + j * 256;
        dst[idx] = (v[j] - mu) * rs * lw[idx] + lb[idx];
    }
}

// ---- split-K FC: In staged to LDS, compile-time KC -> fully unrolled K-loop ----
template<int KC>
__global__ __launch_bounds__(256) void k_fc_splitk(const float* __restrict__ In, const float* __restrict__ W,
                                                   float* __restrict__ partial, int K, int Nc) {
    __shared__ float in_s[16][KC];
    int t = threadIdx.x;
    int k0 = blockIdx.y * KC;
    for (int idx = t; idx < 16 * KC; idx += 256) {
        int r = idx / KC, kk = idx % KC;
        in_s[r][kk] = In[(size_t)r * K + k0 + kk];
    }
    __syncthreads();
    int col = blockIdx.x * 256 + t;
    if (col < Nc) {
        float acc[16] = {};
#pragma unroll
        for (int kk = 0; kk < KC; kk++) {
            float w = W[(size_t)(k0 + kk) * Nc + col];
#pragma unroll
            for (int r = 0; r < 16; r++) acc[r] += in_s[r][kk] * w;
        }
        float* pp = partial + ((size_t)blockIdx.y * 16) * Nc + col;
#pragma unroll
        for (int r = 0; r < 16; r++) pp[(size_t)r * Nc] = acc[r];
    }
}

// ---- split-K FC with fused prev-partial reduce (compile-time KSprev, unrolled) ----
template<int KSprev, int KC>
__global__ __launch_bounds__(256) void k_fc_skm(const float* __restrict__ pprev, const float* __restrict__ bprev,
                                                int Kprev, const float* __restrict__ W,
                                                float* __restrict__ partial, int Nc) {
    __shared__ float in_s[16][KC];
    int t = threadIdx.x;
    int k0 = blockIdx.y * KC;
    for (int idx = t; idx < 16 * KC; idx += 256) {
        int r = idx / KC, kk = idx % KC;
        int g = k0 + kk;
        float s = bprev[g];
#pragma unroll
        for (int j = 0; j < KSprev; j++) s += pprev[((size_t)j * 16 + r) * Kprev + g];
        s = s > 0.f ? s : expm1f(s);
        in_s[r][kk] = s;
    }
    __syncthreads();
    int col = blockIdx.x * 256 + t;
    if (col < Nc) {
        float acc[16] = {};
#pragma unroll
        for (int kk = 0; kk < KC; kk++) {
            float w = W[(size_t)(k0 + kk) * Nc + col];
#pragma unroll
            for (int r = 0; r < 16; r++) acc[r] += in_s[r][kk] * w;
        }
        float* pp = partial + ((size_t)blockIdx.y * 16) * Nc + col;
#pragma unroll
        for (int r = 0; r < 16; r++) pp[(size_t)r * Nc] = acc[r];
    }
}

// ---- final: reduce partial2 (32 slabs, constant loop -> auto-unrolled) + ELU + last ----
__global__ __launch_bounds__(256) void k_last_m(const float* __restrict__ p2, const float* __restrict__ b2,
                                                const float* __restrict__ lastw, const float* __restrict__ lastb,
                                                float* __restrict__ out) {
    __shared__ float e2_s[16 * OMIC];
    int t = threadIdx.x;
    for (int idx = t; idx < 16 * OMIC; idx += 256) {
        int r = idx >> 7, col = idx & 127;
        float s = b2[col];
#pragma unroll
        for (int j = 0; j < 32; j++) s += p2[((size_t)j * 16 + r) * OMIC + col];
        s = s > 0.f ? s : expm1f(s);
        e2_s[idx] = s;
    }
    __syncthreads();
    if (t < 32) {
        int r = t >> 1, c = t & 1;
        float s = lastb[c];
#pragma unroll
        for (int k = 0; k < OMIC; k++) s += e2_s[r * OMIC + k] * lastw[k * OUTD + c];
        out[r * OUTD + c] = s;
    }
}

extern "C" void kernel_launch(void* const* d_in, const int* in_sizes, int n_in,
                              void* d_out, int out_size, void* d_ws, size_t ws_size,
                              hipStream_t stream) {
    (void)in_sizes; (void)n_in; (void)out_size; (void)ws_size;
    const float* x        = (const float*)d_in[0];
    const int*   ei       = (const int*)d_in[1];
    const float* w1       = (const float*)d_in[2];
    const float* att_src1 = (const float*)d_in[3];
    const float* att_dst1 = (const float*)d_in[4];
    const float* bias1    = (const float*)d_in[5];
    const float* pool1_w  = (const float*)d_in[6];
    const float* pool1_b  = (const float*)d_in[7];
    const float* w2       = (const float*)d_in[8];
    const float* att_src2 = (const float*)d_in[9];
    const float* att_dst2 = (const float*)d_in[10];
    const float* bias2    = (const float*)d_in[11];
    const float* pool2_w  = (const float*)d_in[12];
    const float* pool2_b  = (const float*)d_in[13];
    const float* ln_w     = (const float*)d_in[14];
    const float* ln_b     = (const float*)d_in[15];
    const float* enc0_w   = (const float*)d_in[16];
    const float* enc0_b   = (const float*)d_in[17];
    const float* enc1_w   = (const float*)d_in[18];
    const float* enc1_b   = (const float*)d_in[19];
    const float* enc2_w   = (const float*)d_in[20];
    const float* enc2_b   = (const float*)d_in[21];
    const float* last_w   = (const float*)d_in[22];
    const float* last_b   = (const float*)d_in[23];
    float* out = (float*)d_out;

    char* p = (char*)d_ws;
    auto alloc = [&](size_t bytes) -> void* {
        void* r = (void*)p;
        p += (bytes + 255) & ~(size_t)255;
        return r;
    };
    unsigned short* xwb  = (unsigned short*)alloc((size_t)NTN * HC * 2);
    unsigned short* hb   = (unsigned short*)alloc((size_t)NTN * HC * 2);
    unsigned short* xb   = (unsigned short*)alloc((size_t)NTN * IN_CH * 2);
    unsigned short* w1t  = (unsigned short*)alloc((size_t)HC * IN_CH * 2);
    unsigned short* w2t  = (unsigned short*)alloc((size_t)HC * HC * 2);
    float* a_src  = (float*)alloc((size_t)NTN * 4 * 4);
    float* a_dst  = (float*)alloc((size_t)NTN * 4 * 4);
    float* xmean  = (float*)alloc((size_t)NTN * 4);
    float* x1pre  = (float*)alloc((size_t)NTN * 4);
    float* x2pre  = (float*)alloc((size_t)NTN * 4);
    float* feat   = (float*)alloc((size_t)BB * 3 * NN * 4);
    float* part0  = (float*)alloc((size_t)96 * 16 * FC0 * 4);
    float* part1  = (float*)alloc((size_t)64 * 16 * FC1 * 4);
    float* part2  = (float*)alloc((size_t)32 * 16 * OMIC * 4);
    int*   deg    = (int*)alloc((size_t)NTN * 4);
    int*   rowptr = (int*)alloc((size_t)(NTN + 1) * 4);
    int*   epos   = (int*)alloc((size_t)EREAL * 4);
    int*   csr    = (int*)alloc((size_t)ETOT * 4);

    hipMemsetAsync(deg, 0, (size_t)NTN * 4, stream);

    k_pre<<<PREP_BLKS + DEG_BLKS + CASTW_BLKS, 256, 0, stream>>>(
        x, xb, xmean, ei, deg, epos, w1, w2, w1t, w2t);
    k_scan<<<1, 1024, 0, stream>>>(deg, rowptr, csr);
    k_fill<<<(EREAL + 255) / 256, 256, 0, stream>>>(ei, epos, rowptr, csr);

    // GAT layer 1
    k_gemm_mfma<<<dim3(4, NTN / 128), 256, 0, stream>>>(xb, w1t, IN_CH, att_src1, att_dst1, xwb, a_src, a_dst);
    k_agg<<<NTN / 2, 256, 0, stream>>>(xwb, a_src, a_dst, rowptr, csr, bias1, pool1_w, pool1_b, hb, x1pre);

    // GAT layer 2
    k_gemm_mfma<<<dim3(4, NTN / 128), 256, 0, stream>>>(hb, w2t, HC, att_src2, att_dst2, xwb, a_src, a_dst);
    k_agg<<<NTN / 2, 256, 0, stream>>>(xwb, a_src, a_dst, rowptr, csr, bias2, pool2_w, pool2_b, (unsigned short*)nullptr, x2pre);

    // all three LayerNorms in one dispatch
    k_ln3<<<48, 256, 0, stream>>>(xmean, x1pre, x2pre, ln_w, ln_b, feat);

    // encoder MLP: 4 dispatches, every reduce loop compile-time unrolled
    k_fc_splitk<64><<<dim3(4, 96), 256, 0, stream>>>(feat, enc0_w, part0, 3 * NN, FC0);
    k_fc_skm<96, 16><<<dim3(2, 64), 256, 0, stream>>>(part0, enc0_b, FC0, enc1_w, part1, FC1);
    k_fc_skm<64, 16><<<dim3(1, 32), 256, 0, stream>>>(part1, enc1_b, FC1, enc2_w, part2, OMIC);
    k_last_m<<<1, 256, 0, stream>>>(part2, enc2_b, last_w, last_b, out);
}

// Round 10
// 356.243 us; speedup vs baseline: 1.2127x; 1.2127x over previous
//
#include <hip/hip_runtime.h>
#include <math.h>

#define NTN 32768
#define BB 16
#define NN 2048
#define IN_CH 128
#define HC 256
#define EREAL 524288
#define ETOT (EREAL + NTN)
#define FC0 1024
#define FC1 512
#define OMIC 128
#define OUTD 2
#define CAP 96

#define PREP_BLKS (NTN / 4)
#define DEG_BLKS (EREAL / 256)
#define CASTW_BLKS ((HC * IN_CH + HC * HC) / 256)

typedef __attribute__((ext_vector_type(8))) short bf16x8;
typedef __attribute__((ext_vector_type(4))) float f32x4;

static __device__ __forceinline__ float wave_sum(float v) {
    for (int o = 32; o; o >>= 1) v += __shfl_xor(v, o);
    return v;
}
static __device__ __forceinline__ unsigned short f2bf(float f) {
    unsigned u = __float_as_uint(f);
    unsigned r = (u + 0x7fff + ((u >> 16) & 1)) >> 16;
    return (unsigned short)r;
}
static __device__ __forceinline__ void fma8(uint4 v, float e, float* acc) {
    acc[0] += __uint_as_float(v.x << 16) * e;
    acc[1] += __uint_as_float(v.x & 0xffff0000u) * e;
    acc[2] += __uint_as_float(v.y << 16) * e;
    acc[3] += __uint_as_float(v.y & 0xffff0000u) * e;
    acc[4] += __uint_as_float(v.z << 16) * e;
    acc[5] += __uint_as_float(v.z & 0xffff0000u) * e;
    acc[6] += __uint_as_float(v.w << 16) * e;
    acc[7] += __uint_as_float(v.w & 0xffff0000u) * e;
}

// ---- fused: x->bf16 + mean | deg count + edge slot | weight transpose-casts ----
__global__ __launch_bounds__(256) void k_pre(
    const float* __restrict__ x, unsigned short* __restrict__ xb, float* __restrict__ xmean,
    const int* __restrict__ ei, int* __restrict__ deg, int* __restrict__ epos,
    const float* __restrict__ w1, const float* __restrict__ w2,
    unsigned short* __restrict__ w1t, unsigned short* __restrict__ w2t) {
    int b = blockIdx.x, t = threadIdx.x;
    if (b < PREP_BLKS) {
        int wave = t >> 6, lane = t & 63;
        int n = b * 4 + wave;
        float2 v = *(const float2*)(x + (size_t)n * IN_CH + lane * 2);
        ushort2 o;
        o.x = f2bf(v.x); o.y = f2bf(v.y);
        *(ushort2*)(xb + (size_t)n * IN_CH + lane * 2) = o;
        float s = wave_sum(v.x + v.y);
        if (lane == 0) xmean[n] = s * (1.0f / 128.0f);
    } else if (b < PREP_BLKS + DEG_BLKS) {
        int e = (b - PREP_BLKS) * 256 + t;
        int d = ei[EREAL + e];
        epos[e] = atomicAdd(&deg[d], 1);
    } else {
        int idx = (b - PREP_BLKS - DEG_BLKS) * 256 + t;
        if (idx < HC * IN_CH) {
            int n = idx / IN_CH, k = idx % IN_CH;
            w1t[idx] = f2bf(w1[(size_t)k * HC + n]);
        } else {
            int j = idx - HC * IN_CH;
            int n = j / HC, k = j % HC;
            w2t[j] = f2bf(w2[(size_t)k * HC + n]);
        }
    }
}

// ---- scan degrees -> rowptr; write self-loop at slot 0 of each segment ----
__global__ __launch_bounds__(1024) void k_scan(const int* __restrict__ deg, int* __restrict__ rowptr,
                                               int* __restrict__ csr) {
    __shared__ int sd[1024];
    int t = threadIdx.x;
    int base = t * 32;
    int loc[32];
    int s = 0;
#pragma unroll
    for (int j = 0; j < 32; j++) { int d = deg[base + j] + 1; loc[j] = d; s += d; }
    sd[t] = s; __syncthreads();
    for (int o = 1; o < 1024; o <<= 1) {
        int v = (t >= o) ? sd[t - o] : 0;
        __syncthreads();
        sd[t] += v;
        __syncthreads();
    }
    int run = sd[t] - s;  // exclusive prefix
#pragma unroll
    for (int j = 0; j < 32; j++) {
        rowptr[base + j] = run;
        csr[run] = base + j;   // self-loop at slot 0
        run += loc[j];
    }
    if (t == 1023) rowptr[NTN] = run;
}

// ---- atomic-free CSR fill using precomputed slots ----
__global__ void k_fill(const int* __restrict__ ei, const int* __restrict__ epos,
                       const int* __restrict__ rowptr, int* __restrict__ csr) {
    int e = blockIdx.x * 256 + threadIdx.x;
    if (e >= EREAL) return;
    int s = ei[e], d = ei[EREAL + e];
    csr[rowptr[d] + 1 + epos[e]] = s;
}

// ---- bf16 MFMA GEMM: C[M,256] = A[M,K] @ Bt[256,K]^T, fused att head-dots ----
__global__ __launch_bounds__(256) void k_gemm_mfma(
    const unsigned short* __restrict__ A, const unsigned short* __restrict__ Bt, int K,
    const float* __restrict__ attS, const float* __restrict__ attD,
    unsigned short* __restrict__ Cout, float* __restrict__ aS, float* __restrict__ aD) {
    __shared__ unsigned short As[128][72];
    __shared__ unsigned short Bs[64][72];
    const int t = threadIdx.x;
    const int lane = t & 63, wave = t >> 6;
    const int quad = lane >> 4, l16 = lane & 15;
    const int bx = blockIdx.x, by = blockIdx.y;
    const int arow = t >> 1, acol = (t & 1) * 32;
    const int brow = t >> 2, bcol = (t & 3) * 16;
    const unsigned short* Ag = A + (size_t)(by * 128 + arow) * K + acol;
    const unsigned short* Bg = Bt + (size_t)(bx * 64 + brow) * K + bcol;
    f32x4 acc[2][4] = {};
    for (int k0 = 0; k0 < K; k0 += 64) {
        uint4 a0 = *(const uint4*)(Ag + k0);
        uint4 a1 = *(const uint4*)(Ag + k0 + 8);
        uint4 a2 = *(const uint4*)(Ag + k0 + 16);
        uint4 a3 = *(const uint4*)(Ag + k0 + 24);
        uint4 b0 = *(const uint4*)(Bg + k0);
        uint4 b1 = *(const uint4*)(Bg + k0 + 8);
        __syncthreads();
        *(uint4*)&As[arow][acol +  0] = a0;
        *(uint4*)&As[arow][acol +  8] = a1;
        *(uint4*)&As[arow][acol + 16] = a2;
        *(uint4*)&As[arow][acol + 24] = a3;
        *(uint4*)&Bs[brow][bcol +  0] = b0;
        *(uint4*)&Bs[brow][bcol +  8] = b1;
        __syncthreads();
#pragma unroll
        for (int kc = 0; kc < 64; kc += 32) {
            bf16x8 af[2], bfr[4];
#pragma unroll
            for (int mt = 0; mt < 2; mt++)
                af[mt] = *(const bf16x8*)&As[wave * 32 + mt * 16 + l16][kc + quad * 8];
#pragma unroll
            for (int nt = 0; nt < 4; nt++)
                bfr[nt] = *(const bf16x8*)&Bs[nt * 16 + l16][kc + quad * 8];
#pragma unroll
            for (int mt = 0; mt < 2; mt++)
#pragma unroll
                for (int nt = 0; nt < 4; nt++)
                    acc[mt][nt] = __builtin_amdgcn_mfma_f32_16x16x32_bf16(af[mt], bfr[nt], acc[mt][nt], 0, 0, 0);
        }
    }
    float as_l[4], ad_l[4];
#pragma unroll
    for (int nt = 0; nt < 4; nt++) {
        int gcol = bx * 64 + nt * 16 + l16;
        as_l[nt] = attS[gcol];
        ad_l[nt] = attD[gcol];
    }
#pragma unroll
    for (int mt = 0; mt < 2; mt++) {
#pragma unroll
        for (int reg = 0; reg < 4; reg++) {
            int grow = by * 128 + wave * 32 + mt * 16 + quad * 4 + reg;
            float ps = 0.f, pd = 0.f;
#pragma unroll
            for (int nt = 0; nt < 4; nt++) {
                float v = acc[mt][nt][reg];
                Cout[(size_t)grow * HC + bx * 64 + nt * 16 + l16] = f2bf(v);
                ps += v * as_l[nt];
                pd += v * ad_l[nt];
            }
            for (int o = 8; o; o >>= 1) { ps += __shfl_xor(ps, o); pd += __shfl_xor(pd, o); }
            if (l16 == 0) { aS[grow * 4 + bx] = ps; aD[grow * 4 + bx] = pd; }
        }
    }
}

// ---- attention aggregate: 2 nodes/block, 2 waves/node; half-wave pairing, unroll-4 ----
// NOTE (R9 post-mortem): unroll-8 raised VGPR 32->44, occupancy 69->46%, dur 59->82us.
// TLP > ILP here; keep unroll-4 / VGPR 32.
__global__ __launch_bounds__(256) void k_agg(
    const unsigned short* __restrict__ xw, const float* __restrict__ aS, const float* __restrict__ aD,
    const int* __restrict__ rowptr, const int* __restrict__ csr,
    const float* __restrict__ bias, const float* __restrict__ poolw, const float* __restrict__ poolb,
    unsigned short* __restrict__ hout, float* __restrict__ xpre) {
    __shared__ float ea_s[2][CAP][4];
    __shared__ float part[2][2][256];
    __shared__ float lpart[2][2][4];
    int t = threadIdx.x;
    int wave = t >> 6, lane = t & 63;
    int nd = wave >> 1, half = wave & 1;
    int n = blockIdx.x * 2 + nd;
    int beg = rowptr[n], end = rowptr[n + 1];
    int deg = end - beg;
    int mid = beg + ((deg + 1) >> 1);
    int wbeg = half ? mid : beg;
    int wend = half ? end : mid;
    float4 ad4 = *(const float4*)(aD + n * 4);
    float l0 = 0.f, l1 = 0.f, l2 = 0.f, l3 = 0.f;
    for (int i = wbeg + lane; i < wend; i += 64) {
        int s = csr[i];
        float4 as4 = *(const float4*)(aS + s * 4);
        float a0 = as4.x + ad4.x; a0 = a0 > 0.f ? a0 : 0.2f * a0; float e0 = __expf(a0);
        float a1 = as4.y + ad4.y; a1 = a1 > 0.f ? a1 : 0.2f * a1; float e1 = __expf(a1);
        float a2 = as4.z + ad4.z; a2 = a2 > 0.f ? a2 : 0.2f * a2; float e2 = __expf(a2);
        float a3 = as4.w + ad4.w; a3 = a3 > 0.f ? a3 : 0.2f * a3; float e3 = __expf(a3);
        l0 += e0; l1 += e1; l2 += e2; l3 += e3;
        int j = i - beg;
        if (j < CAP) {
            float4 e4; e4.x = e0; e4.y = e1; e4.z = e2; e4.w = e3;
            *(float4*)&ea_s[nd][j][0] = e4;
        }
    }
    l0 = wave_sum(l0); l1 = wave_sum(l1); l2 = wave_sum(l2); l3 = wave_sum(l3);
    if (lane == 0) {
        lpart[nd][half][0] = l0; lpart[nd][half][1] = l1;
        lpart[nd][half][2] = l2; lpart[nd][half][3] = l3;
    }
    __syncthreads();
    int l31 = lane & 31, hi = lane >> 5;
    int head = l31 >> 3;
    float ilh = 1.0f / (lpart[nd][0][head] + lpart[nd][1][head] + 1e-16f);
    float adh = head == 0 ? ad4.x : head == 1 ? ad4.y : head == 2 ? ad4.z : ad4.w;
    float accA[8] = {}, accB[8] = {};
    const unsigned short* xwc = xw + l31 * 8;
    if (deg <= CAP) {
        int i = wbeg;
        for (; i + 4 <= wend; i += 4) {
            int sA = csr[i + hi];
            int sB = csr[i + 2 + hi];
            float eA = ea_s[nd][i + hi - beg][head];
            float eB = ea_s[nd][i + 2 + hi - beg][head];
            uint4 vA = *(const uint4*)(xwc + (size_t)sA * HC);
            uint4 vB = *(const uint4*)(xwc + (size_t)sB * HC);
            fma8(vA, eA, accA);
            fma8(vB, eB, accB);
        }
        for (; i < wend; i += 2) {
            int idx = i + hi;
            bool ok = idx < wend;
            int sA = csr[ok ? idx : wbeg];
            float eA = ok ? ea_s[nd][idx - beg][head] : 0.f;
            uint4 vA = *(const uint4*)(xwc + (size_t)sA * HC);
            fma8(vA, eA, accA);
        }
    } else {
        for (int i = wbeg; i < wend; i += 2) {
            int idx = i + hi;
            bool ok = idx < wend;
            int sA = csr[ok ? idx : wbeg];
            float a = aS[sA * 4 + head] + adh;
            a = a > 0.f ? a : 0.2f * a;
            float eA = ok ? __expf(a) : 0.f;
            uint4 vA = *(const uint4*)(xwc + (size_t)sA * HC);
            fma8(vA, eA, accA);
        }
    }
    float r8[8];
#pragma unroll
    for (int j = 0; j < 8; j++) {
        float v = accA[j] + accB[j];
        v += __shfl_xor(v, 32);
        r8[j] = v;
    }
    if (hi == 0) {
        float4 q0; q0.x = r8[0]; q0.y = r8[1]; q0.z = r8[2]; q0.w = r8[3];
        float4 q1; q1.x = r8[4]; q1.y = r8[5]; q1.z = r8[6]; q1.w = r8[7];
        *(float4*)&part[nd][half][l31 * 8] = q0;
        *(float4*)&part[nd][half][l31 * 8 + 4] = q1;
    }
    __syncthreads();
    if (half == 0 && hi == 0) {
        float4 p00 = *(const float4*)&part[nd][0][l31 * 8];
        float4 p01 = *(const float4*)&part[nd][0][l31 * 8 + 4];
        float4 p10 = *(const float4*)&part[nd][1][l31 * 8];
        float4 p11 = *(const float4*)&part[nd][1][l31 * 8 + 4];
        float4 b0 = *(const float4*)(bias + l31 * 8);
        float4 b1 = *(const float4*)(bias + l31 * 8 + 4);
        float r[8];
        r[0] = (p00.x + p10.x) * ilh + b0.x;
        r[1] = (p00.y + p10.y) * ilh + b0.y;
        r[2] = (p00.z + p10.z) * ilh + b0.z;
        r[3] = (p00.w + p10.w) * ilh + b0.w;
        r[4] = (p01.x + p11.x) * ilh + b1.x;
        r[5] = (p01.y + p11.y) * ilh + b1.y;
        r[6] = (p01.z + p11.z) * ilh + b1.z;
        r[7] = (p01.w + p11.w) * ilh + b1.w;
#pragma unroll
        for (int j = 0; j < 8; j++) r[j] = r[j] > 0.f ? r[j] : expm1f(r[j]);
        if (hout) {
            uint4 o;
            o.x = (unsigned)f2bf(r[0]) | ((unsigned)f2bf(r[1]) << 16);
            o.y = (unsigned)f2bf(r[2]) | ((unsigned)f2bf(r[3]) << 16);
            o.z = (unsigned)f2bf(r[4]) | ((unsigned)f2bf(r[5]) << 16);
            o.w = (unsigned)f2bf(r[6]) | ((unsigned)f2bf(r[7]) << 16);
            *(uint4*)(hout + (size_t)n * HC + l31 * 8) = o;
        }
        float4 w0 = *(const float4*)(poolw + l31 * 8);
        float4 w1v = *(const float4*)(poolw + l31 * 8 + 4);
        float p = r[0] * w0.x + r[1] * w0.y + r[2] * w0.z + r[3] * w0.w +
                  r[4] * w1v.x + r[5] * w1v.y + r[6] * w1v.z + r[7] * w1v.w;
        for (int o = 16; o; o >>= 1) p += __shfl_xor(p, o);
        if (l31 == 0) xpre[n] = p + poolb[0];
    }
}

// ---- LayerNorm x3: blocks 0-15 xmean->col0, 16-31 x1pre->col1, 32-47 x2pre->col2 ----
__global__ __launch_bounds__(256) void k_ln3(const float* __restrict__ xmean, const float* __restrict__ x1pre,
                                             const float* __restrict__ x2pre, const float* __restrict__ lw,
                                             const float* __restrict__ lb, float* __restrict__ feat) {
    __shared__ float r0[256], r1[256];
    int b = blockIdx.x, t = threadIdx.x;
    int row = b & 15, seg = b >> 4;
    const float* src = (seg == 0 ? xmean : seg == 1 ? x1pre : x2pre) + (size_t)row * NN;
    float* dst = feat + (size_t)row * (3 * NN) + seg * NN;
    float v[8];
    float s = 0.f, s2 = 0.f;
#pragma unroll
    for (int j = 0; j < 8; j++) {
        float x = src[t + j * 256];
        v[j] = x; s += x; s2 += x * x;
    }
    r0[t] = s; r1[t] = s2; __syncthreads();
    for (int o = 128; o; o >>= 1) {
        if (t < o) { r0[t] += r0[t + o]; r1[t] += r1[t + o]; }
        __syncthreads();
    }
    float mu = r0[0] * (1.0f / NN);
    float var = r1[0] * (1.0f / NN) - mu * mu;
    float rs = rsqrtf(var + 1e-5f);
#pragma unroll
    for (int j = 0; j < 8; j++) {
        int idx = t + j * 256;
        dst[idx] = (v[j] - mu) * rs * lw[idx] + lb[idx];
    }
}

// ---- split-K FC: In staged to LDS, compile-time KC -> fully unrolled K-loop ----
template<int KC>
__global__ __launch_bounds__(256) void k_fc_splitk(const float* __restrict__ In, const float* __restrict__ W,
                                                   float* __restrict__ partial, int K, int Nc) {
    __shared__ float in_s[16][KC];
    int t = threadIdx.x;
    int k0 = blockIdx.y * KC;
    for (int idx = t; idx < 16 * KC; idx += 256) {
        int r = idx / KC, kk = idx % KC;
        in_s[r][kk] = In[(size_t)r * K + k0 + kk];
    }
    __syncthreads();
    int col = blockIdx.x * 256 + t;
    if (col < Nc) {
        float acc[16] = {};
#pragma unroll
        for (int kk = 0; kk < KC; kk++) {
            float w = W[(size_t)(k0 + kk) * Nc + col];
#pragma unroll
            for (int r = 0; r < 16; r++) acc[r] += in_s[r][kk] * w;
        }
        float* pp = partial + ((size_t)blockIdx.y * 16) * Nc + col;
#pragma unroll
        for (int r = 0; r < 16; r++) pp[(size_t)r * Nc] = acc[r];
    }
}

// ---- parallel reduce over KS partials: 8 threads/output, compile-time KS ----
template<int KS>
__global__ __launch_bounds__(256) void k_fc_reduce(const float* __restrict__ partial, const float* __restrict__ bias,
                                                   float* __restrict__ Out, int Nc) {
    __shared__ float sm[256];
    int t = threadIdx.x;
    int col = blockIdx.x * 32 + (t & 31);
    int r = blockIdx.y;
    int h = t >> 5;
    float s = 0.f;
#pragma unroll
    for (int i = 0; i < KS / 8; i++)
        s += partial[((size_t)(h + 8 * i) * 16 + r) * Nc + col];
    sm[t] = s;
    __syncthreads();
    if (t < 32) {
        float v = sm[t] + sm[t + 32] + sm[t + 64] + sm[t + 96] +
                  sm[t + 128] + sm[t + 160] + sm[t + 192] + sm[t + 224];
        v += bias[col];
        v = v > 0.f ? v : expm1f(v);
        Out[(size_t)r * Nc + col] = v;
    }
}

// ---- last layer: Out[16,2] = In[16,128] @ W[128,2] + b ----
__global__ __launch_bounds__(256) void k_last(const float* __restrict__ In, const float* __restrict__ W,
                                              const float* __restrict__ b, float* __restrict__ Out) {
    int t = threadIdx.x;
    int r = t >> 4, c = (t >> 3) & 1, ksub = t & 7;
    float s = 0.f;
#pragma unroll
    for (int k = 0; k < OMIC / 8; k++) s += In[r * OMIC + k * 8 + ksub] * W[(k * 8 + ksub) * OUTD + c];
    for (int o = 1; o < 8; o <<= 1) s += __shfl_xor(s, o);
    if (ksub == 0) Out[r * OUTD + c] = s + b[c];
}

extern "C" void kernel_launch(void* const* d_in, const int* in_sizes, int n_in,
                              void* d_out, int out_size, void* d_ws, size_t ws_size,
                              hipStream_t stream) {
    (void)in_sizes; (void)n_in; (void)out_size; (void)ws_size;
    const float* x        = (const float*)d_in[0];
    const int*   ei       = (const int*)d_in[1];
    const float* w1       = (const float*)d_in[2];
    const float* att_src1 = (const float*)d_in[3];
    const float* att_dst1 = (const float*)d_in[4];
    const float* bias1    = (const float*)d_in[5];
    const float* pool1_w  = (const float*)d_in[6];
    const float* pool1_b  = (const float*)d_in[7];
    const float* w2       = (const float*)d_in[8];
    const float* att_src2 = (const float*)d_in[9];
    const float* att_dst2 = (const float*)d_in[10];
    const float* bias2    = (const float*)d_in[11];
    const float* pool2_w  = (const float*)d_in[12];
    const float* pool2_b  = (const float*)d_in[13];
    const float* ln_w     = (const float*)d_in[14];
    const float* ln_b     = (const float*)d_in[15];
    const float* enc0_w   = (const float*)d_in[16];
    const float* enc0_b   = (const float*)d_in[17];
    const float* enc1_w   = (const float*)d_in[18];
    const float* enc1_b   = (const float*)d_in[19];
    const float* enc2_w   = (const float*)d_in[20];
    const float* enc2_b   = (const float*)d_in[21];
    const float* last_w   = (const float*)d_in[22];
    const float* last_b   = (const float*)d_in[23];
    float* out = (float*)d_out;

    char* p = (char*)d_ws;
    auto alloc = [&](size_t bytes) -> void* {
        void* r = (void*)p;
        p += (bytes + 255) & ~(size_t)255;
        return r;
    };
    unsigned short* xwb  = (unsigned short*)alloc((size_t)NTN * HC * 2);
    unsigned short* hb   = (unsigned short*)alloc((size_t)NTN * HC * 2);
    unsigned short* xb   = (unsigned short*)alloc((size_t)NTN * IN_CH * 2);
    unsigned short* w1t  = (unsigned short*)alloc((size_t)HC * IN_CH * 2);
    unsigned short* w2t  = (unsigned short*)alloc((size_t)HC * HC * 2);
    float* a_src  = (float*)alloc((size_t)NTN * 4 * 4);
    float* a_dst  = (float*)alloc((size_t)NTN * 4 * 4);
    float* xmean  = (float*)alloc((size_t)NTN * 4);
    float* x1pre  = (float*)alloc((size_t)NTN * 4);
    float* x2pre  = (float*)alloc((size_t)NTN * 4);
    float* feat   = (float*)alloc((size_t)BB * 3 * NN * 4);
    float* e0     = (float*)alloc((size_t)BB * FC0 * 4);
    float* e1     = (float*)alloc((size_t)BB * FC1 * 4);
    float* e2     = (float*)alloc((size_t)BB * OMIC * 4);
    float* part0  = (float*)alloc((size_t)96 * 16 * FC0 * 4);
    float* part1  = (float*)alloc((size_t)64 * 16 * FC1 * 4);
    float* part2  = (float*)alloc((size_t)32 * 16 * OMIC * 4);
    int*   deg    = (int*)alloc((size_t)NTN * 4);
    int*   rowptr = (int*)alloc((size_t)(NTN + 1) * 4);
    int*   epos   = (int*)alloc((size_t)EREAL * 4);
    int*   csr    = (int*)alloc((size_t)ETOT * 4);

    hipMemsetAsync(deg, 0, (size_t)NTN * 4, stream);

    k_pre<<<PREP_BLKS + DEG_BLKS + CASTW_BLKS, 256, 0, stream>>>(
        x, xb, xmean, ei, deg, epos, w1, w2, w1t, w2t);
    k_scan<<<1, 1024, 0, stream>>>(deg, rowptr, csr);
    k_fill<<<(EREAL + 255) / 256, 256, 0, stream>>>(ei, epos, rowptr, csr);

    // GAT layer 1
    k_gemm_mfma<<<dim3(4, NTN / 128), 256, 0, stream>>>(xb, w1t, IN_CH, att_src1, att_dst1, xwb, a_src, a_dst);
    k_agg<<<NTN / 2, 256, 0, stream>>>(xwb, a_src, a_dst, rowptr, csr, bias1, pool1_w, pool1_b, hb, x1pre);

    // GAT layer 2
    k_gemm_mfma<<<dim3(4, NTN / 128), 256, 0, stream>>>(hb, w2t, HC, att_src2, att_dst2, xwb, a_src, a_dst);
    k_agg<<<NTN / 2, 256, 0, stream>>>(xwb, a_src, a_dst, rowptr, csr, bias2, pool2_w, pool2_b, (unsigned short*)nullptr, x2pre);

    // all three LayerNorms in one dispatch
    k_ln3<<<48, 256, 0, stream>>>(xmean, x1pre, x2pre, ln_w, ln_b, feat);

    // encoder MLP: split-K with compile-time-unrolled loops + parallel reduces
    k_fc_splitk<64><<<dim3(4, 96), 256, 0, stream>>>(feat, enc0_w, part0, 3 * NN, FC0);
    k_fc_reduce<96><<<dim3(FC0 / 32, 16), 256, 0, stream>>>(part0, enc0_b, e0, FC0);
    k_fc_splitk<16><<<dim3(2, 64), 256, 0, stream>>>(e0, enc1_w, part1, FC0, FC1);
    k_fc_reduce<64><<<dim3(FC1 / 32, 16), 256, 0, stream>>>(part1, enc1_b, e1, FC1);
    k_fc_splitk<16><<<dim3(1, 32), 256, 0, stream>>>(e1, enc2_w, part2, FC1, OMIC);
    k_fc_reduce<32><<<dim3(OMIC / 32, 16), 256, 0, stream>>>(part2, enc2_b, e2, OMIC);
    k_last<<<1, 256, 0, stream>>>(e2, last_w, last_b, out);
}

// Round 11
// 345.896 us; speedup vs baseline: 1.2490x; 1.0299x over previous
//
#include <hip/hip_runtime.h>
#include <math.h>

#define NTN 32768
#define BB 16
#define NN 2048
#define IN_CH 128
#define HC 256
#define EREAL 524288
#define ETOT (EREAL + NTN)
#define FC0 1024
#define FC1 512
#define OMIC 128
#define OUTD 2
#define CAP 96

#define PREP_BLKS (NTN / 4)
#define DEG_BLKS (EREAL / 256)
#define CASTW_BLKS ((HC * IN_CH + HC * HC) / 256)
#define GEMM_YB (NTN / 128)
#define FILL_YB 512   // 512*4 blocks * 256 threads = 524288 edges

typedef __attribute__((ext_vector_type(8))) short bf16x8;
typedef __attribute__((ext_vector_type(4))) float f32x4;
typedef __attribute__((ext_vector_type(2))) float f32x2;

static __device__ __forceinline__ float wave_sum(float v) {
    for (int o = 32; o; o >>= 1) v += __shfl_xor(v, o);
    return v;
}
static __device__ __forceinline__ unsigned short f2bf(float f) {
    unsigned u = __float_as_uint(f);
    unsigned r = (u + 0x7fff + ((u >> 16) & 1)) >> 16;
    return (unsigned short)r;
}
// packed fp32 FMA: acc = ab * e2 + acc  (v_pk_fma_f32, gfx90a+)
static __device__ __forceinline__ void pkfma(f32x2& acc, f32x2 ab, f32x2 e2) {
    asm("v_pk_fma_f32 %0, %1, %2, %0" : "+v"(acc) : "v"(ab), "v"(e2));
}
static __device__ __forceinline__ void fma8pk(uint4 v, f32x2 e2, f32x2* acc) {
    f32x2 p;
    p.x = __uint_as_float(v.x << 16); p.y = __uint_as_float(v.x & 0xffff0000u);
    pkfma(acc[0], p, e2);
    p.x = __uint_as_float(v.y << 16); p.y = __uint_as_float(v.y & 0xffff0000u);
    pkfma(acc[1], p, e2);
    p.x = __uint_as_float(v.z << 16); p.y = __uint_as_float(v.z & 0xffff0000u);
    pkfma(acc[2], p, e2);
    p.x = __uint_as_float(v.w << 16); p.y = __uint_as_float(v.w & 0xffff0000u);
    pkfma(acc[3], p, e2);
}

// ---- fused: x->bf16 + mean | deg count + edge slot | weight transpose-casts ----
__global__ __launch_bounds__(256) void k_pre(
    const float* __restrict__ x, unsigned short* __restrict__ xb, float* __restrict__ xmean,
    const int* __restrict__ ei, int* __restrict__ deg, int* __restrict__ epos,
    const float* __restrict__ w1, const float* __restrict__ w2,
    unsigned short* __restrict__ w1t, unsigned short* __restrict__ w2t) {
    int b = blockIdx.x, t = threadIdx.x;
    if (b < PREP_BLKS) {
        int wave = t >> 6, lane = t & 63;
        int n = b * 4 + wave;
        float2 v = *(const float2*)(x + (size_t)n * IN_CH + lane * 2);
        ushort2 o;
        o.x = f2bf(v.x); o.y = f2bf(v.y);
        *(ushort2*)(xb + (size_t)n * IN_CH + lane * 2) = o;
        float s = wave_sum(v.x + v.y);
        if (lane == 0) xmean[n] = s * (1.0f / 128.0f);
    } else if (b < PREP_BLKS + DEG_BLKS) {
        int e = (b - PREP_BLKS) * 256 + t;
        int d = ei[EREAL + e];
        epos[e] = atomicAdd(&deg[d], 1);
    } else {
        int idx = (b - PREP_BLKS - DEG_BLKS) * 256 + t;
        if (idx < HC * IN_CH) {
            int n = idx / IN_CH, k = idx % IN_CH;
            w1t[idx] = f2bf(w1[(size_t)k * HC + n]);
        } else {
            int j = idx - HC * IN_CH;
            int n = j / HC, k = j % HC;
            w2t[j] = f2bf(w2[(size_t)k * HC + n]);
        }
    }
}

// ---- scan degrees -> rowptr; write self-loop at slot 0 of each segment ----
__global__ __launch_bounds__(1024) void k_scan(const int* __restrict__ deg, int* __restrict__ rowptr,
                                               int* __restrict__ csr) {
    __shared__ int sd[1024];
    int t = threadIdx.x;
    int base = t * 32;
    int loc[32];
    int s = 0;
#pragma unroll
    for (int j = 0; j < 32; j++) { int d = deg[base + j] + 1; loc[j] = d; s += d; }
    sd[t] = s; __syncthreads();
    for (int o = 1; o < 1024; o <<= 1) {
        int v = (t >= o) ? sd[t - o] : 0;
        __syncthreads();
        sd[t] += v;
        __syncthreads();
    }
    int run = sd[t] - s;  // exclusive prefix
#pragma unroll
    for (int j = 0; j < 32; j++) {
        rowptr[base + j] = run;
        csr[run] = base + j;   // self-loop at slot 0
        run += loc[j];
    }
    if (t == 1023) rowptr[NTN] = run;
}

// ---- bf16 MFMA GEMM (+ optional fused CSR-fill blocks at by >= GEMM_YB) ----
__global__ __launch_bounds__(256) void k_gemm_mfma(
    const unsigned short* __restrict__ A, const unsigned short* __restrict__ Bt, int K,
    const float* __restrict__ attS, const float* __restrict__ attD,
    unsigned short* __restrict__ Cout, float* __restrict__ aS, float* __restrict__ aD,
    const int* __restrict__ ei, const int* __restrict__ epos,
    const int* __restrict__ rowptr, int* __restrict__ csr) {
    __shared__ unsigned short As[128][72];
    __shared__ unsigned short Bs[64][72];
    const int t = threadIdx.x;
    const int bx = blockIdx.x, by = blockIdx.y;
    if (by >= GEMM_YB) {
        // fused atomic-free CSR fill
        int e = (((by - GEMM_YB) * 4 + bx)) * 256 + t;
        int s = ei[e], d = ei[EREAL + e];
        csr[rowptr[d] + 1 + epos[e]] = s;
        return;
    }
    const int lane = t & 63, wave = t >> 6;
    const int quad = lane >> 4, l16 = lane & 15;
    const int arow = t >> 1, acol = (t & 1) * 32;
    const int brow = t >> 2, bcol = (t & 3) * 16;
    const unsigned short* Ag = A + (size_t)(by * 128 + arow) * K + acol;
    const unsigned short* Bg = Bt + (size_t)(bx * 64 + brow) * K + bcol;
    f32x4 acc[2][4] = {};
    for (int k0 = 0; k0 < K; k0 += 64) {
        uint4 a0 = *(const uint4*)(Ag + k0);
        uint4 a1 = *(const uint4*)(Ag + k0 + 8);
        uint4 a2 = *(const uint4*)(Ag + k0 + 16);
        uint4 a3 = *(const uint4*)(Ag + k0 + 24);
        uint4 b0 = *(const uint4*)(Bg + k0);
        uint4 b1 = *(const uint4*)(Bg + k0 + 8);
        __syncthreads();
        *(uint4*)&As[arow][acol +  0] = a0;
        *(uint4*)&As[arow][acol +  8] = a1;
        *(uint4*)&As[arow][acol + 16] = a2;
        *(uint4*)&As[arow][acol + 24] = a3;
        *(uint4*)&Bs[brow][bcol +  0] = b0;
        *(uint4*)&Bs[brow][bcol +  8] = b1;
        __syncthreads();
#pragma unroll
        for (int kc = 0; kc < 64; kc += 32) {
            bf16x8 af[2], bfr[4];
#pragma unroll
            for (int mt = 0; mt < 2; mt++)
                af[mt] = *(const bf16x8*)&As[wave * 32 + mt * 16 + l16][kc + quad * 8];
#pragma unroll
            for (int nt = 0; nt < 4; nt++)
                bfr[nt] = *(const bf16x8*)&Bs[nt * 16 + l16][kc + quad * 8];
#pragma unroll
            for (int mt = 0; mt < 2; mt++)
#pragma unroll
                for (int nt = 0; nt < 4; nt++)
                    acc[mt][nt] = __builtin_amdgcn_mfma_f32_16x16x32_bf16(af[mt], bfr[nt], acc[mt][nt], 0, 0, 0);
        }
    }
    float as_l[4], ad_l[4];
#pragma unroll
    for (int nt = 0; nt < 4; nt++) {
        int gcol = bx * 64 + nt * 16 + l16;
        as_l[nt] = attS[gcol];
        ad_l[nt] = attD[gcol];
    }
#pragma unroll
    for (int mt = 0; mt < 2; mt++) {
#pragma unroll
        for (int reg = 0; reg < 4; reg++) {
            int grow = by * 128 + wave * 32 + mt * 16 + quad * 4 + reg;
            float ps = 0.f, pd = 0.f;
#pragma unroll
            for (int nt = 0; nt < 4; nt++) {
                float v = acc[mt][nt][reg];
                Cout[(size_t)grow * HC + bx * 64 + nt * 16 + l16] = f2bf(v);
                ps += v * as_l[nt];
                pd += v * ad_l[nt];
            }
            for (int o = 8; o; o >>= 1) { ps += __shfl_xor(ps, o); pd += __shfl_xor(pd, o); }
            if (l16 == 0) { aS[grow * 4 + bx] = ps; aD[grow * 4 + bx] = pd; }
        }
    }
}

// ---- attention aggregate: 2 nodes/block, 2 waves/node; half-wave pairing, unroll-4 ----
// R9 lesson: unroll-8 cost occupancy (VGPR 44) — keep unroll-4 / VGPR~32. R11: v_pk_fma_f32.
__global__ __launch_bounds__(256) void k_agg(
    const unsigned short* __restrict__ xw, const float* __restrict__ aS, const float* __restrict__ aD,
    const int* __restrict__ rowptr, const int* __restrict__ csr,
    const float* __restrict__ bias, const float* __restrict__ poolw, const float* __restrict__ poolb,
    unsigned short* __restrict__ hout, float* __restrict__ xpre) {
    __shared__ float ea_s[2][CAP][4];
    __shared__ float part[2][2][256];
    __shared__ float lpart[2][2][4];
    int t = threadIdx.x;
    int wave = t >> 6, lane = t & 63;
    int nd = wave >> 1, half = wave & 1;
    int n = blockIdx.x * 2 + nd;
    int beg = rowptr[n], end = rowptr[n + 1];
    int deg = end - beg;
    int mid = beg + ((deg + 1) >> 1);
    int wbeg = half ? mid : beg;
    int wend = half ? end : mid;
    float4 ad4 = *(const float4*)(aD + n * 4);
    float l0 = 0.f, l1 = 0.f, l2 = 0.f, l3 = 0.f;
    for (int i = wbeg + lane; i < wend; i += 64) {
        int s = csr[i];
        float4 as4 = *(const float4*)(aS + s * 4);
        float a0 = as4.x + ad4.x; a0 = a0 > 0.f ? a0 : 0.2f * a0; float e0 = __expf(a0);
        float a1 = as4.y + ad4.y; a1 = a1 > 0.f ? a1 : 0.2f * a1; float e1 = __expf(a1);
        float a2 = as4.z + ad4.z; a2 = a2 > 0.f ? a2 : 0.2f * a2; float e2 = __expf(a2);
        float a3 = as4.w + ad4.w; a3 = a3 > 0.f ? a3 : 0.2f * a3; float e3 = __expf(a3);
        l0 += e0; l1 += e1; l2 += e2; l3 += e3;
        int j = i - beg;
        if (j < CAP) {
            float4 e4; e4.x = e0; e4.y = e1; e4.z = e2; e4.w = e3;
            *(float4*)&ea_s[nd][j][0] = e4;
        }
    }
    l0 = wave_sum(l0); l1 = wave_sum(l1); l2 = wave_sum(l2); l3 = wave_sum(l3);
    if (lane == 0) {
        lpart[nd][half][0] = l0; lpart[nd][half][1] = l1;
        lpart[nd][half][2] = l2; lpart[nd][half][3] = l3;
    }
    __syncthreads();
    int l31 = lane & 31, hi = lane >> 5;
    int head = l31 >> 3;
    float ilh = 1.0f / (lpart[nd][0][head] + lpart[nd][1][head] + 1e-16f);
    float adh = head == 0 ? ad4.x : head == 1 ? ad4.y : head == 2 ? ad4.z : ad4.w;
    f32x2 accA[4] = {}, accB[4] = {};
    const unsigned short* xwc = xw + l31 * 8;
    if (deg <= CAP) {
        int i = wbeg;
        for (; i + 4 <= wend; i += 4) {
            int sA = csr[i + hi];
            int sB = csr[i + 2 + hi];
            float eA = ea_s[nd][i + hi - beg][head];
            float eB = ea_s[nd][i + 2 + hi - beg][head];
            uint4 vA = *(const uint4*)(xwc + (size_t)sA * HC);
            uint4 vB = *(const uint4*)(xwc + (size_t)sB * HC);
            f32x2 eA2; eA2.x = eA; eA2.y = eA;
            f32x2 eB2; eB2.x = eB; eB2.y = eB;
            fma8pk(vA, eA2, accA);
            fma8pk(vB, eB2, accB);
        }
        for (; i < wend; i += 2) {
            int idx = i + hi;
            bool ok = idx < wend;
            int sA = csr[ok ? idx : wbeg];
            float eA = ok ? ea_s[nd][idx - beg][head] : 0.f;
            uint4 vA = *(const uint4*)(xwc + (size_t)sA * HC);
            f32x2 eA2; eA2.x = eA; eA2.y = eA;
            fma8pk(vA, eA2, accA);
        }
    } else {
        for (int i = wbeg; i < wend; i += 2) {
            int idx = i + hi;
            bool ok = idx < wend;
            int sA = csr[ok ? idx : wbeg];
            float a = aS[sA * 4 + head] + adh;
            a = a > 0.f ? a : 0.2f * a;
            float eA = ok ? __expf(a) : 0.f;
            uint4 vA = *(const uint4*)(xwc + (size_t)sA * HC);
            f32x2 eA2; eA2.x = eA; eA2.y = eA;
            fma8pk(vA, eA2, accA);
        }
    }
    float r8[8];
#pragma unroll
    for (int j = 0; j < 8; j++) {
        float v = accA[j >> 1][j & 1] + accB[j >> 1][j & 1];
        v += __shfl_xor(v, 32);
        r8[j] = v;
    }
    if (hi == 0) {
        float4 q0; q0.x = r8[0]; q0.y = r8[1]; q0.z = r8[2]; q0.w = r8[3];
        float4 q1; q1.x = r8[4]; q1.y = r8[5]; q1.z = r8[6]; q1.w = r8[7];
        *(float4*)&part[nd][half][l31 * 8] = q0;
        *(float4*)&part[nd][half][l31 * 8 + 4] = q1;
    }
    __syncthreads();
    if (half == 0 && hi == 0) {
        float4 p00 = *(const float4*)&part[nd][0][l31 * 8];
        float4 p01 = *(const float4*)&part[nd][0][l31 * 8 + 4];
        float4 p10 = *(const float4*)&part[nd][1][l31 * 8];
        float4 p11 = *(const float4*)&part[nd][1][l31 * 8 + 4];
        float4 b0 = *(const float4*)(bias + l31 * 8);
        float4 b1 = *(const float4*)(bias + l31 * 8 + 4);
        float r[8];
        r[0] = (p00.x + p10.x) * ilh + b0.x;
        r[1] = (p00.y + p10.y) * ilh + b0.y;
        r[2] = (p00.z + p10.z) * ilh + b0.z;
        r[3] = (p00.w + p10.w) * ilh + b0.w;
        r[4] = (p01.x + p11.x) * ilh + b1.x;
        r[5] = (p01.y + p11.y) * ilh + b1.y;
        r[6] = (p01.z + p11.z) * ilh + b1.z;
        r[7] = (p01.w + p11.w) * ilh + b1.w;
#pragma unroll
        for (int j = 0; j < 8; j++) r[j] = r[j] > 0.f ? r[j] : expm1f(r[j]);
        if (hout) {
            uint4 o;
            o.x = (unsigned)f2bf(r[0]) | ((unsigned)f2bf(r[1]) << 16);
            o.y = (unsigned)f2bf(r[2]) | ((unsigned)f2bf(r[3]) << 16);
            o.z = (unsigned)f2bf(r[4]) | ((unsigned)f2bf(r[5]) << 16);
            o.w = (unsigned)f2bf(r[6]) | ((unsigned)f2bf(r[7]) << 16);
            *(uint4*)(hout + (size_t)n * HC + l31 * 8) = o;
        }
        float4 w0 = *(const float4*)(poolw + l31 * 8);
        float4 w1v = *(const float4*)(poolw + l31 * 8 + 4);
        float p = r[0] * w0.x + r[1] * w0.y + r[2] * w0.z + r[3] * w0.w +
                  r[4] * w1v.x + r[5] * w1v.y + r[6] * w1v.z + r[7] * w1v.w;
        for (int o = 16; o; o >>= 1) p += __shfl_xor(p, o);
        if (l31 == 0) xpre[n] = p + poolb[0];
    }
}

// ---- LayerNorm x3: blocks 0-15 xmean->col0, 16-31 x1pre->col1, 32-47 x2pre->col2 ----
__global__ __launch_bounds__(256) void k_ln3(const float* __restrict__ xmean, const float* __restrict__ x1pre,
                                             const float* __restrict__ x2pre, const float* __restrict__ lw,
                                             const float* __restrict__ lb, float* __restrict__ feat) {
    __shared__ float r0[256], r1[256];
    int b = blockIdx.x, t = threadIdx.x;
    int row = b & 15, seg = b >> 4;
    const float* src = (seg == 0 ? xmean : seg == 1 ? x1pre : x2pre) + (size_t)row * NN;
    float* dst = feat + (size_t)row * (3 * NN) + seg * NN;
    float v[8];
    float s = 0.f, s2 = 0.f;
#pragma unroll
    for (int j = 0; j < 8; j++) {
        float x = src[t + j * 256];
        v[j] = x; s += x; s2 += x * x;
    }
    r0[t] = s; r1[t] = s2; __syncthreads();
    for (int o = 128; o; o >>= 1) {
        if (t < o) { r0[t] += r0[t + o]; r1[t] += r1[t + o]; }
        __syncthreads();
    }
    float mu = r0[0] * (1.0f / NN);
    float var = r1[0] * (1.0f / NN) - mu * mu;
    float rs = rsqrtf(var + 1e-5f);
#pragma unroll
    for (int j = 0; j < 8; j++) {
        int idx = t + j * 256;
        dst[idx] = (v[j] - mu) * rs * lw[idx] + lb[idx];
    }
}

// ---- split-K FC: In staged to LDS, compile-time KC -> fully unrolled K-loop ----
template<int KC>
__global__ __launch_bounds__(256) void k_fc_splitk(const float* __restrict__ In, const float* __restrict__ W,
                                                   float* __restrict__ partial, int K, int Nc) {
    __shared__ float in_s[16][KC];
    int t = threadIdx.x;
    int k0 = blockIdx.y * KC;
    for (int idx = t; idx < 16 * KC; idx += 256) {
        int r = idx / KC, kk = idx % KC;
        in_s[r][kk] = In[(size_t)r * K + k0 + kk];
    }
    __syncthreads();
    int col = blockIdx.x * 256 + t;
    if (col < Nc) {
        float acc[16] = {};
#pragma unroll
        for (int kk = 0; kk < KC; kk++) {
            float w = W[(size_t)(k0 + kk) * Nc + col];
#pragma unroll
            for (int r = 0; r < 16; r++) acc[r] += in_s[r][kk] * w;
        }
        float* pp = partial + ((size_t)blockIdx.y * 16) * Nc + col;
#pragma unroll
        for (int r = 0; r < 16; r++) pp[(size_t)r * Nc] = acc[r];
    }
}

// ---- parallel reduce over KS partials: 8 threads/output, compile-time KS ----
template<int KS>
__global__ __launch_bounds__(256) void k_fc_reduce(const float* __restrict__ partial, const float* __restrict__ bias,
                                                   float* __restrict__ Out, int Nc) {
    __shared__ float sm[256];
    int t = threadIdx.x;
    int col = blockIdx.x * 32 + (t & 31);
    int r = blockIdx.y;
    int h = t >> 5;
    float s = 0.f;
#pragma unroll
    for (int i = 0; i < KS / 8; i++)
        s += partial[((size_t)(h + 8 * i) * 16 + r) * Nc + col];
    sm[t] = s;
    __syncthreads();
    if (t < 32) {
        float v = sm[t] + sm[t + 32] + sm[t + 64] + sm[t + 96] +
                  sm[t + 128] + sm[t + 160] + sm[t + 192] + sm[t + 224];
        v += bias[col];
        v = v > 0.f ? v : expm1f(v);
        Out[(size_t)r * Nc + col] = v;
    }
}

// ---- last layer: Out[16,2] = In[16,128] @ W[128,2] + b ----
__global__ __launch_bounds__(256) void k_last(const float* __restrict__ In, const float* __restrict__ W,
                                              const float* __restrict__ b, float* __restrict__ Out) {
    int t = threadIdx.x;
    int r = t >> 4, c = (t >> 3) & 1, ksub = t & 7;
    float s = 0.f;
#pragma unroll
    for (int k = 0; k < OMIC / 8; k++) s += In[r * OMIC + k * 8 + ksub] * W[(k * 8 + ksub) * OUTD + c];
    for (int o = 1; o < 8; o <<= 1) s += __shfl_xor(s, o);
    if (ksub == 0) Out[r * OUTD + c] = s + b[c];
}

extern "C" void kernel_launch(void* const* d_in, const int* in_sizes, int n_in,
                              void* d_out, int out_size, void* d_ws, size_t ws_size,
                              hipStream_t stream) {
    (void)in_sizes; (void)n_in; (void)out_size; (void)ws_size;
    const float* x        = (const float*)d_in[0];
    const int*   ei       = (const int*)d_in[1];
    const float* w1       = (const float*)d_in[2];
    const float* att_src1 = (const float*)d_in[3];
    const float* att_dst1 = (const float*)d_in[4];
    const float* bias1    = (const float*)d_in[5];
    const float* pool1_w  = (const float*)d_in[6];
    const float* pool1_b  = (const float*)d_in[7];
    const float* w2       = (const float*)d_in[8];
    const float* att_src2 = (const float*)d_in[9];
    const float* att_dst2 = (const float*)d_in[10];
    const float* bias2    = (const float*)d_in[11];
    const float* pool2_w  = (const float*)d_in[12];
    const float* pool2_b  = (const float*)d_in[13];
    const float* ln_w     = (const float*)d_in[14];
    const float* ln_b     = (const float*)d_in[15];
    const float* enc0_w   = (const float*)d_in[16];
    const float* enc0_b   = (const float*)d_in[17];
    const float* enc1_w   = (const float*)d_in[18];
    const float* enc1_b   = (const float*)d_in[19];
    const float* enc2_w   = (const float*)d_in[20];
    const float* enc2_b   = (const float*)d_in[21];
    const float* last_w   = (const float*)d_in[22];
    const float* last_b   = (const float*)d_in[23];
    float* out = (float*)d_out;

    char* p = (char*)d_ws;
    auto alloc = [&](size_t bytes) -> void* {
        void* r = (void*)p;
        p += (bytes + 255) & ~(size_t)255;
        return r;
    };
    unsigned short* xwb  = (unsigned short*)alloc((size_t)NTN * HC * 2);
    unsigned short* hb   = (unsigned short*)alloc((size_t)NTN * HC * 2);
    unsigned short* xb   = (unsigned short*)alloc((size_t)NTN * IN_CH * 2);
    unsigned short* w1t  = (unsigned short*)alloc((size_t)HC * IN_CH * 2);
    unsigned short* w2t  = (unsigned short*)alloc((size_t)HC * HC * 2);
    float* a_src  = (float*)alloc((size_t)NTN * 4 * 4);
    float* a_dst  = (float*)alloc((size_t)NTN * 4 * 4);
    float* xmean  = (float*)alloc((size_t)NTN * 4);
    float* x1pre  = (float*)alloc((size_t)NTN * 4);
    float* x2pre  = (float*)alloc((size_t)NTN * 4);
    float* feat   = (float*)alloc((size_t)BB * 3 * NN * 4);
    float* e0     = (float*)alloc((size_t)BB * FC0 * 4);
    float* e1     = (float*)alloc((size_t)BB * FC1 * 4);
    float* e2     = (float*)alloc((size_t)BB * OMIC * 4);
    float* part0  = (float*)alloc((size_t)96 * 16 * FC0 * 4);
    float* part1  = (float*)alloc((size_t)64 * 16 * FC1 * 4);
    float* part2  = (float*)alloc((size_t)32 * 16 * OMIC * 4);
    int*   deg    = (int*)alloc((size_t)NTN * 4);
    int*   rowptr = (int*)alloc((size_t)(NTN + 1) * 4);
    int*   epos   = (int*)alloc((size_t)EREAL * 4);
    int*   csr    = (int*)alloc((size_t)ETOT * 4);

    hipMemsetAsync(deg, 0, (size_t)NTN * 4, stream);

    k_pre<<<PREP_BLKS + DEG_BLKS + CASTW_BLKS, 256, 0, stream>>>(
        x, xb, xmean, ei, deg, epos, w1, w2, w1t, w2t);
    k_scan<<<1, 1024, 0, stream>>>(deg, rowptr, csr);

    // GAT layer 1 (+ fused CSR fill blocks)
    k_gemm_mfma<<<dim3(4, GEMM_YB + FILL_YB), 256, 0, stream>>>(
        xb, w1t, IN_CH, att_src1, att_dst1, xwb, a_src, a_dst, ei, epos, rowptr, csr);
    k_agg<<<NTN / 2, 256, 0, stream>>>(xwb, a_src, a_dst, rowptr, csr, bias1, pool1_w, pool1_b, hb, x1pre);

    // GAT layer 2
    k_gemm_mfma<<<dim3(4, GEMM_YB), 256, 0, stream>>>(
        hb, w2t, HC, att_src2, att_dst2, xwb, a_src, a_dst, ei, epos, rowptr, csr);
    k_agg<<<NTN / 2, 256, 0, stream>>>(xwb, a_src, a_dst, rowptr, csr, bias2, pool2_w, pool2_b, (unsigned short*)nullptr, x2pre);

    // all three LayerNorms in one dispatch
    k_ln3<<<48, 256, 0, stream>>>(xmean, x1pre, x2pre, ln_w, ln_b, feat);

    // encoder MLP: split-K with compile-time-unrolled loops + parallel reduces
    k_fc_splitk<64><<<dim3(4, 96), 256, 0, stream>>>(feat, enc0_w, part0, 3 * NN, FC0);
    k_fc_reduce<96><<<dim3(FC0 / 32, 16), 256, 0, stream>>>(part0, enc0_b, e0, FC0);
    k_fc_splitk<16><<<dim3(2, 64), 256, 0, stream>>>(e0, enc1_w, part1, FC0, FC1);
    k_fc_reduce<64><<<dim3(FC1 / 32, 16), 256, 0, stream>>>(part1, enc1_b, e1, FC1);
    k_fc_splitk<16><<<dim3(1, 32), 256, 0, stream>>>(e1, enc2_w, part2, FC1, OMIC);
    k_fc_reduce<32><<<dim3(OMIC / 32, 16), 256, 0, stream>>>(part2, enc2_b, e2, OMIC);
    k_last<<<1, 256, 0, stream>>>(e2, last_w, last_b, out);
}

// Round 12
// 334.380 us; speedup vs baseline: 1.2920x; 1.0344x over previous
//
#include <hip/hip_runtime.h>
#include <math.h>

#define NTN 32768
#define BB 16
#define NN 2048
#define IN_CH 128
#define HC 256
#define EREAL 524288
#define ETOT (EREAL + NTN)
#define FC0 1024
#define FC1 512
#define OMIC 128
#define OUTD 2
#define CAP 96

#define PREP_BLKS (NTN / 4)
#define DEG_BLKS (EREAL / 256)
#define CASTW_BLKS ((HC * IN_CH + HC * HC) / 256)
#define GEMM_YB (NTN / 128)
#define FILL_YB 512   // 512*4 blocks * 256 threads = 524288 edges

typedef __attribute__((ext_vector_type(8))) short bf16x8;
typedef __attribute__((ext_vector_type(4))) float f32x4;
typedef __attribute__((ext_vector_type(2))) float f32x2;

static __device__ __forceinline__ float wave_sum(float v) {
    for (int o = 32; o; o >>= 1) v += __shfl_xor(v, o);
    return v;
}
static __device__ __forceinline__ unsigned short f2bf(float f) {
    unsigned u = __float_as_uint(f);
    unsigned r = (u + 0x7fff + ((u >> 16) & 1)) >> 16;
    return (unsigned short)r;
}
// packed fp32 FMA: acc = ab * e2 + acc  (v_pk_fma_f32, gfx90a+)
static __device__ __forceinline__ void pkfma(f32x2& acc, f32x2 ab, f32x2 e2) {
    asm("v_pk_fma_f32 %0, %1, %2, %0" : "+v"(acc) : "v"(ab), "v"(e2));
}
static __device__ __forceinline__ void fma8pk(uint4 v, f32x2 e2, f32x2* acc) {
    f32x2 p;
    p.x = __uint_as_float(v.x << 16); p.y = __uint_as_float(v.x & 0xffff0000u);
    pkfma(acc[0], p, e2);
    p.x = __uint_as_float(v.y << 16); p.y = __uint_as_float(v.y & 0xffff0000u);
    pkfma(acc[1], p, e2);
    p.x = __uint_as_float(v.z << 16); p.y = __uint_as_float(v.z & 0xffff0000u);
    pkfma(acc[2], p, e2);
    p.x = __uint_as_float(v.w << 16); p.y = __uint_as_float(v.w & 0xffff0000u);
    pkfma(acc[3], p, e2);
}

// ---- fused: x->bf16 + mean | deg count + edge slot | weight transpose-casts ----
__global__ __launch_bounds__(256) void k_pre(
    const float* __restrict__ x, unsigned short* __restrict__ xb, float* __restrict__ xmean,
    const int* __restrict__ ei, int* __restrict__ deg, int* __restrict__ epos,
    const float* __restrict__ w1, const float* __restrict__ w2,
    unsigned short* __restrict__ w1t, unsigned short* __restrict__ w2t) {
    int b = blockIdx.x, t = threadIdx.x;
    if (b < PREP_BLKS) {
        int wave = t >> 6, lane = t & 63;
        int n = b * 4 + wave;
        float2 v = *(const float2*)(x + (size_t)n * IN_CH + lane * 2);
        ushort2 o;
        o.x = f2bf(v.x); o.y = f2bf(v.y);
        *(ushort2*)(xb + (size_t)n * IN_CH + lane * 2) = o;
        float s = wave_sum(v.x + v.y);
        if (lane == 0) xmean[n] = s * (1.0f / 128.0f);
    } else if (b < PREP_BLKS + DEG_BLKS) {
        int e = (b - PREP_BLKS) * 256 + t;
        int d = ei[EREAL + e];
        epos[e] = atomicAdd(&deg[d], 1);
    } else {
        int idx = (b - PREP_BLKS - DEG_BLKS) * 256 + t;
        if (idx < HC * IN_CH) {
            int n = idx / IN_CH, k = idx % IN_CH;
            w1t[idx] = f2bf(w1[(size_t)k * HC + n]);
        } else {
            int j = idx - HC * IN_CH;
            int n = j / HC, k = j % HC;
            w2t[j] = f2bf(w2[(size_t)k * HC + n]);
        }
    }
}

// ---- scan degrees -> rowptr; write self-loop at slot 0 of each segment ----
__global__ __launch_bounds__(1024) void k_scan(const int* __restrict__ deg, int* __restrict__ rowptr,
                                               int* __restrict__ csr) {
    __shared__ int sd[1024];
    int t = threadIdx.x;
    int base = t * 32;
    int loc[32];
    int s = 0;
#pragma unroll
    for (int j = 0; j < 32; j++) { int d = deg[base + j] + 1; loc[j] = d; s += d; }
    sd[t] = s; __syncthreads();
    for (int o = 1; o < 1024; o <<= 1) {
        int v = (t >= o) ? sd[t - o] : 0;
        __syncthreads();
        sd[t] += v;
        __syncthreads();
    }
    int run = sd[t] - s;  // exclusive prefix
#pragma unroll
    for (int j = 0; j < 32; j++) {
        rowptr[base + j] = run;
        csr[run] = base + j;   // self-loop at slot 0
        run += loc[j];
    }
    if (t == 1023) rowptr[NTN] = run;
}

// ---- bf16 MFMA GEMM (+ optional fused CSR-fill blocks at by >= GEMM_YB) ----
__global__ __launch_bounds__(256) void k_gemm_mfma(
    const unsigned short* __restrict__ A, const unsigned short* __restrict__ Bt, int K,
    const float* __restrict__ attS, const float* __restrict__ attD,
    unsigned short* __restrict__ Cout, float* __restrict__ aS, float* __restrict__ aD,
    const int* __restrict__ ei, const int* __restrict__ epos,
    const int* __restrict__ rowptr, int* __restrict__ csr) {
    __shared__ unsigned short As[128][72];
    __shared__ unsigned short Bs[64][72];
    const int t = threadIdx.x;
    const int bx = blockIdx.x, by = blockIdx.y;
    if (by >= GEMM_YB) {
        // fused atomic-free CSR fill
        int e = (((by - GEMM_YB) * 4 + bx)) * 256 + t;
        int s = ei[e], d = ei[EREAL + e];
        csr[rowptr[d] + 1 + epos[e]] = s;
        return;
    }
    const int lane = t & 63, wave = t >> 6;
    const int quad = lane >> 4, l16 = lane & 15;
    const int arow = t >> 1, acol = (t & 1) * 32;
    const int brow = t >> 2, bcol = (t & 3) * 16;
    const unsigned short* Ag = A + (size_t)(by * 128 + arow) * K + acol;
    const unsigned short* Bg = Bt + (size_t)(bx * 64 + brow) * K + bcol;
    f32x4 acc[2][4] = {};
    for (int k0 = 0; k0 < K; k0 += 64) {
        uint4 a0 = *(const uint4*)(Ag + k0);
        uint4 a1 = *(const uint4*)(Ag + k0 + 8);
        uint4 a2 = *(const uint4*)(Ag + k0 + 16);
        uint4 a3 = *(const uint4*)(Ag + k0 + 24);
        uint4 b0 = *(const uint4*)(Bg + k0);
        uint4 b1 = *(const uint4*)(Bg + k0 + 8);
        __syncthreads();
        *(uint4*)&As[arow][acol +  0] = a0;
        *(uint4*)&As[arow][acol +  8] = a1;
        *(uint4*)&As[arow][acol + 16] = a2;
        *(uint4*)&As[arow][acol + 24] = a3;
        *(uint4*)&Bs[brow][bcol +  0] = b0;
        *(uint4*)&Bs[brow][bcol +  8] = b1;
        __syncthreads();
#pragma unroll
        for (int kc = 0; kc < 64; kc += 32) {
            bf16x8 af[2], bfr[4];
#pragma unroll
            for (int mt = 0; mt < 2; mt++)
                af[mt] = *(const bf16x8*)&As[wave * 32 + mt * 16 + l16][kc + quad * 8];
#pragma unroll
            for (int nt = 0; nt < 4; nt++)
                bfr[nt] = *(const bf16x8*)&Bs[nt * 16 + l16][kc + quad * 8];
#pragma unroll
            for (int mt = 0; mt < 2; mt++)
#pragma unroll
                for (int nt = 0; nt < 4; nt++)
                    acc[mt][nt] = __builtin_amdgcn_mfma_f32_16x16x32_bf16(af[mt], bfr[nt], acc[mt][nt], 0, 0, 0);
        }
    }
    float as_l[4], ad_l[4];
#pragma unroll
    for (int nt = 0; nt < 4; nt++) {
        int gcol = bx * 64 + nt * 16 + l16;
        as_l[nt] = attS[gcol];
        ad_l[nt] = attD[gcol];
    }
#pragma unroll
    for (int mt = 0; mt < 2; mt++) {
#pragma unroll
        for (int reg = 0; reg < 4; reg++) {
            int grow = by * 128 + wave * 32 + mt * 16 + quad * 4 + reg;
            float ps = 0.f, pd = 0.f;
#pragma unroll
            for (int nt = 0; nt < 4; nt++) {
                float v = acc[mt][nt][reg];
                Cout[(size_t)grow * HC + bx * 64 + nt * 16 + l16] = f2bf(v);
                ps += v * as_l[nt];
                pd += v * ad_l[nt];
            }
            for (int o = 8; o; o >>= 1) { ps += __shfl_xor(ps, o); pd += __shfl_xor(pd, o); }
            if (l16 == 0) { aS[grow * 4 + bx] = ps; aD[grow * 4 + bx] = pd; }
        }
    }
}

// ---- attention aggregate: 2 nodes/block, 2 waves/node; half-wave pairing, unroll-4 ----
// R9: unroll-8 cost occupancy — keep unroll-4 / VGPR~32.
// R12: phase-1 wave_sum eliminated; softmax denominator computed in epilogue from ea_s.
__global__ __launch_bounds__(256) void k_agg(
    const unsigned short* __restrict__ xw, const float* __restrict__ aS, const float* __restrict__ aD,
    const int* __restrict__ rowptr, const int* __restrict__ csr,
    const float* __restrict__ bias, const float* __restrict__ poolw, const float* __restrict__ poolb,
    unsigned short* __restrict__ hout, float* __restrict__ xpre) {
    __shared__ float ea_s[2][CAP][4];
    __shared__ float part[2][2][256];
    __shared__ float lpart[2][2][4];   // used only on the deg>CAP fallback path
    int t = threadIdx.x;
    int wave = t >> 6, lane = t & 63;
    int nd = wave >> 1, half = wave & 1;
    int n = blockIdx.x * 2 + nd;
    int beg = rowptr[n], end = rowptr[n + 1];
    int deg = end - beg;
    int mid = beg + ((deg + 1) >> 1);
    int wbeg = half ? mid : beg;
    int wend = half ? end : mid;
    float4 ad4 = *(const float4*)(aD + n * 4);
    if (deg <= CAP) {
        // phase 1: exp(leaky(alpha)) lane-parallel into LDS; no reduction here
        for (int i = wbeg + lane; i < wend; i += 64) {
            int s = csr[i];
            float4 as4 = *(const float4*)(aS + s * 4);
            float a0 = as4.x + ad4.x; a0 = a0 > 0.f ? a0 : 0.2f * a0;
            float a1 = as4.y + ad4.y; a1 = a1 > 0.f ? a1 : 0.2f * a1;
            float a2 = as4.z + ad4.z; a2 = a2 > 0.f ? a2 : 0.2f * a2;
            float a3 = as4.w + ad4.w; a3 = a3 > 0.f ? a3 : 0.2f * a3;
            float4 e4;
            e4.x = __expf(a0); e4.y = __expf(a1); e4.z = __expf(a2); e4.w = __expf(a3);
            *(float4*)&ea_s[nd][i - beg][0] = e4;
        }
    } else {
        // fallback (statistically never): wave_sum path for denominators
        float l0 = 0.f, l1 = 0.f, l2 = 0.f, l3 = 0.f;
        for (int i = wbeg + lane; i < wend; i += 64) {
            int s = csr[i];
            float4 as4 = *(const float4*)(aS + s * 4);
            float a0 = as4.x + ad4.x; a0 = a0 > 0.f ? a0 : 0.2f * a0; l0 += __expf(a0);
            float a1 = as4.y + ad4.y; a1 = a1 > 0.f ? a1 : 0.2f * a1; l1 += __expf(a1);
            float a2 = as4.z + ad4.z; a2 = a2 > 0.f ? a2 : 0.2f * a2; l2 += __expf(a2);
            float a3 = as4.w + ad4.w; a3 = a3 > 0.f ? a3 : 0.2f * a3; l3 += __expf(a3);
        }
        l0 = wave_sum(l0); l1 = wave_sum(l1); l2 = wave_sum(l2); l3 = wave_sum(l3);
        if (lane == 0) {
            lpart[nd][half][0] = l0; lpart[nd][half][1] = l1;
            lpart[nd][half][2] = l2; lpart[nd][half][3] = l3;
        }
    }
    __syncthreads();
    int l31 = lane & 31, hi = lane >> 5;
    int head = l31 >> 3;
    f32x2 accA[4] = {}, accB[4] = {};
    const unsigned short* xwc = xw + l31 * 8;
    if (deg <= CAP) {
        int i = wbeg;
        for (; i + 4 <= wend; i += 4) {
            int sA = csr[i + hi];
            int sB = csr[i + 2 + hi];
            float eA = ea_s[nd][i + hi - beg][head];
            float eB = ea_s[nd][i + 2 + hi - beg][head];
            uint4 vA = *(const uint4*)(xwc + (size_t)sA * HC);
            uint4 vB = *(const uint4*)(xwc + (size_t)sB * HC);
            f32x2 eA2; eA2.x = eA; eA2.y = eA;
            f32x2 eB2; eB2.x = eB; eB2.y = eB;
            fma8pk(vA, eA2, accA);
            fma8pk(vB, eB2, accB);
        }
        for (; i < wend; i += 2) {
            int idx = i + hi;
            bool ok = idx < wend;
            int sA = csr[ok ? idx : wbeg];
            float eA = ok ? ea_s[nd][idx - beg][head] : 0.f;
            uint4 vA = *(const uint4*)(xwc + (size_t)sA * HC);
            f32x2 eA2; eA2.x = eA; eA2.y = eA;
            fma8pk(vA, eA2, accA);
        }
    } else {
        float adh = head == 0 ? ad4.x : head == 1 ? ad4.y : head == 2 ? ad4.z : ad4.w;
        for (int i = wbeg; i < wend; i += 2) {
            int idx = i + hi;
            bool ok = idx < wend;
            int sA = csr[ok ? idx : wbeg];
            float a = aS[sA * 4 + head] + adh;
            a = a > 0.f ? a : 0.2f * a;
            float eA = ok ? __expf(a) : 0.f;
            uint4 vA = *(const uint4*)(xwc + (size_t)sA * HC);
            f32x2 eA2; eA2.x = eA; eA2.y = eA;
            fma8pk(vA, eA2, accA);
        }
    }
    float r8[8];
#pragma unroll
    for (int j = 0; j < 8; j++) {
        float v = accA[j >> 1][j & 1] + accB[j >> 1][j & 1];
        v += __shfl_xor(v, 32);
        r8[j] = v;
    }
    if (hi == 0) {
        float4 q0; q0.x = r8[0]; q0.y = r8[1]; q0.z = r8[2]; q0.w = r8[3];
        float4 q1; q1.x = r8[4]; q1.y = r8[5]; q1.z = r8[6]; q1.w = r8[7];
        *(float4*)&part[nd][half][l31 * 8] = q0;
        *(float4*)&part[nd][half][l31 * 8 + 4] = q1;
    }
    __syncthreads();
    if (half == 0 && hi == 0) {
        // softmax denominator from ea_s: 8 lanes per head, strided partial sums + 3 shfl
        float ilh;
        if (deg <= CAP) {
            float lsum = 0.f;
            for (int j = (l31 & 7); j < deg; j += 8) lsum += ea_s[nd][j][head];
            lsum += __shfl_xor(lsum, 1);
            lsum += __shfl_xor(lsum, 2);
            lsum += __shfl_xor(lsum, 4);
            ilh = 1.0f / (lsum + 1e-16f);
        } else {
            ilh = 1.0f / (lpart[nd][0][head] + lpart[nd][1][head] + 1e-16f);
        }
        float4 p00 = *(const float4*)&part[nd][0][l31 * 8];
        float4 p01 = *(const float4*)&part[nd][0][l31 * 8 + 4];
        float4 p10 = *(const float4*)&part[nd][1][l31 * 8];
        float4 p11 = *(const float4*)&part[nd][1][l31 * 8 + 4];
        float4 b0 = *(const float4*)(bias + l31 * 8);
        float4 b1 = *(const float4*)(bias + l31 * 8 + 4);
        float r[8];
        r[0] = (p00.x + p10.x) * ilh + b0.x;
        r[1] = (p00.y + p10.y) * ilh + b0.y;
        r[2] = (p00.z + p10.z) * ilh + b0.z;
        r[3] = (p00.w + p10.w) * ilh + b0.w;
        r[4] = (p01.x + p11.x) * ilh + b1.x;
        r[5] = (p01.y + p11.y) * ilh + b1.y;
        r[6] = (p01.z + p11.z) * ilh + b1.z;
        r[7] = (p01.w + p11.w) * ilh + b1.w;
#pragma unroll
        for (int j = 0; j < 8; j++) r[j] = r[j] > 0.f ? r[j] : expm1f(r[j]);
        if (hout) {
            uint4 o;
            o.x = (unsigned)f2bf(r[0]) | ((unsigned)f2bf(r[1]) << 16);
            o.y = (unsigned)f2bf(r[2]) | ((unsigned)f2bf(r[3]) << 16);
            o.z = (unsigned)f2bf(r[4]) | ((unsigned)f2bf(r[5]) << 16);
            o.w = (unsigned)f2bf(r[6]) | ((unsigned)f2bf(r[7]) << 16);
            *(uint4*)(hout + (size_t)n * HC + l31 * 8) = o;
        }
        float4 w0 = *(const float4*)(poolw + l31 * 8);
        float4 w1v = *(const float4*)(poolw + l31 * 8 + 4);
        float p = r[0] * w0.x + r[1] * w0.y + r[2] * w0.z + r[3] * w0.w +
                  r[4] * w1v.x + r[5] * w1v.y + r[6] * w1v.z + r[7] * w1v.w;
        for (int o = 16; o; o >>= 1) p += __shfl_xor(p, o);
        if (l31 == 0) xpre[n] = p + poolb[0];
    }
}

// ---- LayerNorm x3: blocks 0-15 xmean->col0, 16-31 x1pre->col1, 32-47 x2pre->col2 ----
__global__ __launch_bounds__(256) void k_ln3(const float* __restrict__ xmean, const float* __restrict__ x1pre,
                                             const float* __restrict__ x2pre, const float* __restrict__ lw,
                                             const float* __restrict__ lb, float* __restrict__ feat) {
    __shared__ float r0[256], r1[256];
    int b = blockIdx.x, t = threadIdx.x;
    int row = b & 15, seg = b >> 4;
    const float* src = (seg == 0 ? xmean : seg == 1 ? x1pre : x2pre) + (size_t)row * NN;
    float* dst = feat + (size_t)row * (3 * NN) + seg * NN;
    float v[8];
    float s = 0.f, s2 = 0.f;
#pragma unroll
    for (int j = 0; j < 8; j++) {
        float x = src[t + j * 256];
        v[j] = x; s += x; s2 += x * x;
    }
    r0[t] = s; r1[t] = s2; __syncthreads();
    for (int o = 128; o; o >>= 1) {
        if (t < o) { r0[t] += r0[t + o]; r1[t] += r1[t + o]; }
        __syncthreads();
    }
    float mu = r0[0] * (1.0f / NN);
    float var = r1[0] * (1.0f / NN) - mu * mu;
    float rs = rsqrtf(var + 1e-5f);
#pragma unroll
    for (int j = 0; j < 8; j++) {
        int idx = t + j * 256;
        dst[idx] = (v[j] - mu) * rs * lw[idx] + lb[idx];
    }
}

// ---- split-K FC: In staged to LDS, compile-time KC -> fully unrolled K-loop ----
template<int KC>
__global__ __launch_bounds__(256) void k_fc_splitk(const float* __restrict__ In, const float* __restrict__ W,
                                                   float* __restrict__ partial, int K, int Nc) {
    __shared__ float in_s[16][KC];
    int t = threadIdx.x;
    int k0 = blockIdx.y * KC;
    for (int idx = t; idx < 16 * KC; idx += 256) {
        int r = idx / KC, kk = idx % KC;
        in_s[r][kk] = In[(size_t)r * K + k0 + kk];
    }
    __syncthreads();
    int col = blockIdx.x * 256 + t;
    if (col < Nc) {
        float acc[16] = {};
#pragma unroll
        for (int kk = 0; kk < KC; kk++) {
            float w = W[(size_t)(k0 + kk) * Nc + col];
#pragma unroll
            for (int r = 0; r < 16; r++) acc[r] += in_s[r][kk] * w;
        }
        float* pp = partial + ((size_t)blockIdx.y * 16) * Nc + col;
#pragma unroll
        for (int r = 0; r < 16; r++) pp[(size_t)r * Nc] = acc[r];
    }
}

// ---- parallel reduce over KS partials: 8 threads/output, compile-time KS ----
template<int KS>
__global__ __launch_bounds__(256) void k_fc_reduce(const float* __restrict__ partial, const float* __restrict__ bias,
                                                   float* __restrict__ Out, int Nc) {
    __shared__ float sm[256];
    int t = threadIdx.x;
    int col = blockIdx.x * 32 + (t & 31);
    int r = blockIdx.y;
    int h = t >> 5;
    float s = 0.f;
#pragma unroll
    for (int i = 0; i < KS / 8; i++)
        s += partial[((size_t)(h + 8 * i) * 16 + r) * Nc + col];
    sm[t] = s;
    __syncthreads();
    if (t < 32) {
        float v = sm[t] + sm[t + 32] + sm[t + 64] + sm[t + 96] +
                  sm[t + 128] + sm[t + 160] + sm[t + 192] + sm[t + 224];
        v += bias[col];
        v = v > 0.f ? v : expm1f(v);
        Out[(size_t)r * Nc + col] = v;
    }
}

// ---- last layer: Out[16,2] = In[16,128] @ W[128,2] + b ----
__global__ __launch_bounds__(256) void k_last(const float* __restrict__ In, const float* __restrict__ W,
                                              const float* __restrict__ b, float* __restrict__ Out) {
    int t = threadIdx.x;
    int r = t >> 4, c = (t >> 3) & 1, ksub = t & 7;
    float s = 0.f;
#pragma unroll
    for (int k = 0; k < OMIC / 8; k++) s += In[r * OMIC + k * 8 + ksub] * W[(k * 8 + ksub) * OUTD + c];
    for (int o = 1; o < 8; o <<= 1) s += __shfl_xor(s, o);
    if (ksub == 0) Out[r * OUTD + c] = s + b[c];
}

extern "C" void kernel_launch(void* const* d_in, const int* in_sizes, int n_in,
                              void* d_out, int out_size, void* d_ws, size_t ws_size,
                              hipStream_t stream) {
    (void)in_sizes; (void)n_in; (void)out_size; (void)ws_size;
    const float* x        = (const float*)d_in[0];
    const int*   ei       = (const int*)d_in[1];
    const float* w1       = (const float*)d_in[2];
    const float* att_src1 = (const float*)d_in[3];
    const float* att_dst1 = (const float*)d_in[4];
    const float* bias1    = (const float*)d_in[5];
    const float* pool1_w  = (const float*)d_in[6];
    const float* pool1_b  = (const float*)d_in[7];
    const float* w2       = (const float*)d_in[8];
    const float* att_src2 = (const float*)d_in[9];
    const float* att_dst2 = (const float*)d_in[10];
    const float* bias2    = (const float*)d_in[11];
    const float* pool2_w  = (const float*)d_in[12];
    const float* pool2_b  = (const float*)d_in[13];
    const float* ln_w     = (const float*)d_in[14];
    const float* ln_b     = (const float*)d_in[15];
    const float* enc0_w   = (const float*)d_in[16];
    const float* enc0_b   = (const float*)d_in[17];
    const float* enc1_w   = (const float*)d_in[18];
    const float* enc1_b   = (const float*)d_in[19];
    const float* enc2_w   = (const float*)d_in[20];
    const float* enc2_b   = (const float*)d_in[21];
    const float* last_w   = (const float*)d_in[22];
    const float* last_b   = (const float*)d_in[23];
    float* out = (float*)d_out;

    char* p = (char*)d_ws;
    auto alloc = [&](size_t bytes) -> void* {
        void* r = (void*)p;
        p += (bytes + 255) & ~(size_t)255;
        return r;
    };
    unsigned short* xwb  = (unsigned short*)alloc((size_t)NTN * HC * 2);
    unsigned short* hb   = (unsigned short*)alloc((size_t)NTN * HC * 2);
    unsigned short* xb   = (unsigned short*)alloc((size_t)NTN * IN_CH * 2);
    unsigned short* w1t  = (unsigned short*)alloc((size_t)HC * IN_CH * 2);
    unsigned short* w2t  = (unsigned short*)alloc((size_t)HC * HC * 2);
    float* a_src  = (float*)alloc((size_t)NTN * 4 * 4);
    float* a_dst  = (float*)alloc((size_t)NTN * 4 * 4);
    float* xmean  = (float*)alloc((size_t)NTN * 4);
    float* x1pre  = (float*)alloc((size_t)NTN * 4);
    float* x2pre  = (float*)alloc((size_t)NTN * 4);
    float* feat   = (float*)alloc((size_t)BB * 3 * NN * 4);
    float* e0     = (float*)alloc((size_t)BB * FC0 * 4);
    float* e1     = (float*)alloc((size_t)BB * FC1 * 4);
    float* e2     = (float*)alloc((size_t)BB * OMIC * 4);
    float* part0  = (float*)alloc((size_t)96 * 16 * FC0 * 4);
    float* part1  = (float*)alloc((size_t)64 * 16 * FC1 * 4);
    float* part2  = (float*)alloc((size_t)32 * 16 * OMIC * 4);
    int*   deg    = (int*)alloc((size_t)NTN * 4);
    int*   rowptr = (int*)alloc((size_t)(NTN + 1) * 4);
    int*   epos   = (int*)alloc((size_t)EREAL * 4);
    int*   csr    = (int*)alloc((size_t)ETOT * 4);

    hipMemsetAsync(deg, 0, (size_t)NTN * 4, stream);

    k_pre<<<PREP_BLKS + DEG_BLKS + CASTW_BLKS, 256, 0, stream>>>(
        x, xb, xmean, ei, deg, epos, w1, w2, w1t, w2t);
    k_scan<<<1, 1024, 0, stream>>>(deg, rowptr, csr);

    // GAT layer 1 (+ fused CSR fill blocks)
    k_gemm_mfma<<<dim3(4, GEMM_YB + FILL_YB), 256, 0, stream>>>(
        xb, w1t, IN_CH, att_src1, att_dst1, xwb, a_src, a_dst, ei, epos, rowptr, csr);
    k_agg<<<NTN / 2, 256, 0, stream>>>(xwb, a_src, a_dst, rowptr, csr, bias1, pool1_w, pool1_b, hb, x1pre);

    // GAT layer 2
    k_gemm_mfma<<<dim3(4, GEMM_YB), 256, 0, stream>>>(
        hb, w2t, HC, att_src2, att_dst2, xwb, a_src, a_dst, ei, epos, rowptr, csr);
    k_agg<<<NTN / 2, 256, 0, stream>>>(xwb, a_src, a_dst, rowptr, csr, bias2, pool2_w, pool2_b, (unsigned short*)nullptr, x2pre);

    // all three LayerNorms in one dispatch
    k_ln3<<<48, 256, 0, stream>>>(xmean, x1pre, x2pre, ln_w, ln_b, feat);

    // encoder MLP: split-K with compile-time-unrolled loops + parallel reduces
    k_fc_splitk<64><<<dim3(4, 96), 256, 0, stream>>>(feat, enc0_w, part0, 3 * NN, FC0);
    k_fc_reduce<96><<<dim3(FC0 / 32, 16), 256, 0, stream>>>(part0, enc0_b, e0, FC0);
    k_fc_splitk<16><<<dim3(2, 64), 256, 0, stream>>>(e0, enc1_w, part1, FC0, FC1);
    k_fc_reduce<64><<<dim3(FC1 / 32, 16), 256, 0, stream>>>(part1, enc1_b, e1, FC1);
    k_fc_splitk<16><<<dim3(1, 32), 256, 0, stream>>>(e1, enc2_w, part2, FC1, OMIC);
    k_fc_reduce<32><<<dim3(OMIC / 32, 16), 256, 0, stream>>>(part2, enc2_b, e2, OMIC);
    k_last<<<1, 256, 0, stream>>>(e2, last_w, last_b, out);
}